// Round 8
// baseline (152.081 us; speedup 1.0000x reference)
//
#include <hip/hip_runtime.h>
#include <math.h>
#include <stdint.h>

typedef __attribute__((ext_vector_type(4))) float f32x4;
typedef __attribute__((ext_vector_type(8))) short bf16x8;

constexpr int NB = 2;       // B
constexpr int NS = 2048;    // S
constexpr int NM = 1024;    // D_MODEL
constexpr int NH = 16;      // H
constexpr int ND = 64;      // D
constexpr int NDI = 1024;   // H*D

__device__ __forceinline__ float bf2f(unsigned short u) {
  uint32_t x = ((uint32_t)u) << 16; float f; __builtin_memcpy(&f, &x, 4); return f;
}
__device__ __forceinline__ unsigned short f2bf(float f) {
  uint32_t x; __builtin_memcpy(&x, &f, 4);
  x += 0x7FFFu + ((x >> 16) & 1u);            // RNE (finite values)
  return (unsigned short)(x >> 16);
}

// ---------------- fused preprocessing: cast x, transpose-cast 5 W, pad Wa ----------------
__global__ __launch_bounds__(256) void k_prep(const float* __restrict__ x,
    const float* __restrict__ w0, const float* __restrict__ w1,
    const float* __restrict__ w2, const float* __restrict__ w3,
    const float* __restrict__ w4, const float* __restrict__ Wa,
    unsigned short* __restrict__ xb,
    unsigned short* __restrict__ t0, unsigned short* __restrict__ t1,
    unsigned short* __restrict__ t2, unsigned short* __restrict__ t3,
    unsigned short* __restrict__ t4, unsigned short* __restrict__ wa_pad) {
  int bid = blockIdx.x;
  if (bid < 2048) {                            // ---- cast x ----
    int i = bid * 256 + threadIdx.x;
    const float4* p = (const float4*)(x + (size_t)i * 8);
    float4 a = p[0], b = p[1];
    unsigned short r[8] = {f2bf(a.x), f2bf(a.y), f2bf(a.z), f2bf(a.w),
                           f2bf(b.x), f2bf(b.y), f2bf(b.z), f2bf(b.w)};
    *(uint4*)(xb + (size_t)i * 8) = *(const uint4*)r;
  } else if (bid < 7168) {                     // ---- castT5 ----
    __shared__ float tile[32][33];
    int w = bid - 2048;
    int z = w >> 10, within = w & 1023;
    const float* src = z == 0 ? w0 : z == 1 ? w1 : z == 2 ? w2 : z == 3 ? w3 : w4;
    unsigned short* dst = z == 0 ? t0 : z == 1 ? t1 : z == 2 ? t2 : z == 3 ? t3 : t4;
    int c0 = (within & 31) * 32, r0 = (within >> 5) * 32;
    int tx = threadIdx.x & 31, ty = threadIdx.x >> 5;
    #pragma unroll
    for (int i = 0; i < 4; i++)
      tile[ty + i * 8][tx] = src[(size_t)(r0 + ty + i * 8) * 1024 + c0 + tx];
    __syncthreads();
    #pragma unroll
    for (int i = 0; i < 4; i++)
      dst[(size_t)(c0 + ty + i * 8) * 1024 + r0 + tx] = f2bf(tile[tx][ty + i * 8]);
  } else {                                     // ---- wa_pad ----
    int idx = (bid - 7168) * 256 + threadIdx.x;
    int h = idx >> 10, k2 = idx & 1023;
    wa_pad[idx] = (h < 16) ? f2bf(Wa[k2 * 16 + h]) : (unsigned short)0;
  }
}

// ---------------- cumsum over s per (b,h) (la already has -softplus) ----------------
__global__ __launch_bounds__(256) void k_cumsum(const float* __restrict__ la,
    float* __restrict__ cum, float* __restrict__ psum, float* __restrict__ psq) {
  int g = blockIdx.x;
  if (threadIdx.x == 0) { psum[g] = 0.f; psq[g] = 0.f; }
  const float* p0 = la + (size_t)g * NS;
  float* out = cum + (size_t)g * NS;
  __shared__ float part[256];
  float v[8]; float sum = 0.f;
  int base = threadIdx.x * 8;
  #pragma unroll
  for (int i = 0; i < 8; i++) { v[i] = p0[base + i]; sum += v[i]; }
  part[threadIdx.x] = sum;
  __syncthreads();
  for (int off = 1; off < 256; off <<= 1) {
    float add = (threadIdx.x >= off) ? part[threadIdx.x - off] : 0.f;
    __syncthreads();
    part[threadIdx.x] += add;
    __syncthreads();
  }
  float run = (threadIdx.x > 0) ? part[threadIdx.x - 1] : 0.f;
  #pragma unroll
  for (int i = 0; i < 8; i++) { run += v[i]; out[base + i] = run; }
}

// ======================================================================
// k_proj2: fused q|k|v|g|la projection. 128x128 tile, BK=64 double-buffer,
// 2-phase (stage-before-compute, one vmcnt(0)+barrier per tile), T2
// source-swizzle, XCD swizzle. 64KB LDS -> 2 blocks/CU (inter-block TLP).
// B = Wcat5 [4224][1024] = Wq^T|Wk^T|Wv^T|Wg^T|wa_pad. Grid 33x32=1056.
// zone 4 (cols 4096+): la epilogue -softplus(acc+ba[h]) -> la[(b*16+h)*2048+s]
// ======================================================================
__global__ __launch_bounds__(256) void k_proj2(const unsigned short* __restrict__ A,
    const unsigned short* __restrict__ Bt, const float* __restrict__ ba,
    unsigned short* __restrict__ q, unsigned short* __restrict__ k,
    unsigned short* __restrict__ v, unsigned short* __restrict__ g,
    float* __restrict__ la) {
  __shared__ unsigned short As[2][128 * 64];   // 32 KB
  __shared__ unsigned short Bs[2][128 * 64];   // 32 KB
  int tid = threadIdx.x;
  int bid = blockIdx.x;                        // 0..1055 (1056 = 8*132)
  int wg = (bid & 7) * 132 + (bid >> 3);       // XCD-bijective
  int by = wg & 31, bx = wg >> 5;              // per-XCD: B-panel reuse
  int row0 = by * 128, col0 = bx * 128;
  int w = tid >> 6, l = tid & 63;
  int wr = w >> 1, wc = w & 1;
  int lr = l & 15, lk = l >> 4;

  auto stage = [&](int t, int bi) {
    #pragma unroll
    for (int i = 0; i < 4; i++) {
      int idx = tid + i * 256;                 // chunk 0..1023
      int r = idx >> 3, c = idx & 7;
      int cs = c ^ (r & 7);                    // pre-swizzled source (T2)
      const unsigned short* srcA = A + (size_t)(row0 + r) * NM + t * 64 + cs * 8;
      __builtin_amdgcn_global_load_lds(
          (const __attribute__((address_space(1))) void*)srcA,
          (__attribute__((address_space(3))) void*)((char*)&As[bi][0] + idx * 16),
          16, 0, 0);
      const unsigned short* srcB = Bt + (size_t)(col0 + r) * NM + t * 64 + cs * 8;
      __builtin_amdgcn_global_load_lds(
          (const __attribute__((address_space(1))) void*)srcB,
          (__attribute__((address_space(3))) void*)((char*)&Bs[bi][0] + idx * 16),
          16, 0, 0);
    }
  };

  stage(0, 0);
  asm volatile("s_waitcnt vmcnt(0)" ::: "memory");
  __builtin_amdgcn_s_barrier();

  f32x4 acc[4][4] = {};
  int cur = 0;
  for (int t = 0; t < 16; ++t) {
    if (t < 15) stage(t + 1, cur ^ 1);         // issue next-tile loads first
    const char* Ap = (const char*)&As[cur][0];
    const char* Bp = (const char*)&Bs[cur][0];
    bf16x8 a[4][2], b[4][2];
    #pragma unroll
    for (int m = 0; m < 4; m++) {
      int ra = wr * 64 + m * 16 + lr;
      #pragma unroll
      for (int kk = 0; kk < 2; kk++)
        a[m][kk] = *(const bf16x8*)(Ap + ra * 128 + (((kk * 4 + lk) ^ (ra & 7)) * 16));
    }
    #pragma unroll
    for (int n = 0; n < 4; n++) {
      int rb = wc * 64 + n * 16 + lr;
      #pragma unroll
      for (int kk = 0; kk < 2; kk++)
        b[n][kk] = *(const bf16x8*)(Bp + rb * 128 + (((kk * 4 + lk) ^ (rb & 7)) * 16));
    }
    __builtin_amdgcn_s_setprio(1);
    #pragma unroll
    for (int kk = 0; kk < 2; kk++)
      #pragma unroll
      for (int m = 0; m < 4; m++)
        #pragma unroll
        for (int n = 0; n < 4; n++)
          acc[m][n] = __builtin_amdgcn_mfma_f32_16x16x32_bf16(a[m][kk], b[n][kk], acc[m][n], 0, 0, 0);
    __builtin_amdgcn_s_setprio(0);
    asm volatile("s_waitcnt vmcnt(0)" ::: "memory");
    __builtin_amdgcn_s_barrier();
    cur ^= 1;
  }

  if (col0 >= 4096) {                          // ---- zone 4: la epilogue ----
    if (wc == 0) {
      float bah = ba[lr];
      #pragma unroll
      for (int m = 0; m < 4; m++) {
        #pragma unroll
        for (int j = 0; j < 4; j++) {
          int row = row0 + wr * 64 + m * 16 + lk * 4 + j;   // token index
          float z = acc[m][0][j] + bah;
          float sp = fmaxf(z, 0.f) + log1pf(expf(-fabsf(z)));
          int bb = row >> 11, s = row & 2047;
          la[((size_t)(bb * 16 + lr)) * 2048 + s] = -sp;
        }
      }
    }
    return;
  }
  #pragma unroll
  for (int m = 0; m < 4; m++) {
    #pragma unroll
    for (int n = 0; n < 4; n++) {
      int col = col0 + wc * 64 + n * 16 + lr;
      int zone = col >> 10;
      unsigned short* dst = zone == 0 ? q : zone == 1 ? k : zone == 2 ? v : g;
      int cb = col & 1023;
      #pragma unroll
      for (int j = 0; j < 4; j++) {
        int row = row0 + wr * 64 + m * 16 + lk * 4 + j;
        float val = acc[m][n][j];
        if (zone <= 1) val = val / (1.f + expf(-val));        // silu
        else if (zone == 3) val = 1.f / (1.f + expf(-val));   // sigmoid
        dst[(size_t)row * 1024 + cb] = f2bf(val);
      }
    }
  }
}

// ======================================================================
// k_out2: out = u @ Wo^T, same 128x128 BK=64 2-phase structure.
// ======================================================================
__global__ __launch_bounds__(256) void k_out2(const unsigned short* __restrict__ A,
    const unsigned short* __restrict__ Bt, float* __restrict__ C) {
  __shared__ unsigned short As[2][128 * 64];
  __shared__ unsigned short Bs[2][128 * 64];
  int tid = threadIdx.x;
  int bid = blockIdx.x;                        // 0..255
  int wg = (bid & 7) * 32 + (bid >> 3);        // XCD-bijective
  int bx = wg & 7, by = wg >> 3;
  int row0 = by * 128, col0 = bx * 128;
  int w = tid >> 6, l = tid & 63;
  int wr = w >> 1, wc = w & 1;
  int lr = l & 15, lk = l >> 4;

  auto stage = [&](int t, int bi) {
    #pragma unroll
    for (int i = 0; i < 4; i++) {
      int idx = tid + i * 256;
      int r = idx >> 3, c = idx & 7;
      int cs = c ^ (r & 7);
      const unsigned short* srcA = A + (size_t)(row0 + r) * NM + t * 64 + cs * 8;
      __builtin_amdgcn_global_load_lds(
          (const __attribute__((address_space(1))) void*)srcA,
          (__attribute__((address_space(3))) void*)((char*)&As[bi][0] + idx * 16),
          16, 0, 0);
      const unsigned short* srcB = Bt + (size_t)(col0 + r) * NM + t * 64 + cs * 8;
      __builtin_amdgcn_global_load_lds(
          (const __attribute__((address_space(1))) void*)srcB,
          (__attribute__((address_space(3))) void*)((char*)&Bs[bi][0] + idx * 16),
          16, 0, 0);
    }
  };

  stage(0, 0);
  asm volatile("s_waitcnt vmcnt(0)" ::: "memory");
  __builtin_amdgcn_s_barrier();

  f32x4 acc[4][4] = {};
  int cur = 0;
  for (int t = 0; t < 16; ++t) {
    if (t < 15) stage(t + 1, cur ^ 1);
    const char* Ap = (const char*)&As[cur][0];
    const char* Bp = (const char*)&Bs[cur][0];
    bf16x8 a[4][2], b[4][2];
    #pragma unroll
    for (int m = 0; m < 4; m++) {
      int ra = wr * 64 + m * 16 + lr;
      #pragma unroll
      for (int kk = 0; kk < 2; kk++)
        a[m][kk] = *(const bf16x8*)(Ap + ra * 128 + (((kk * 4 + lk) ^ (ra & 7)) * 16));
    }
    #pragma unroll
    for (int n = 0; n < 4; n++) {
      int rb = wc * 64 + n * 16 + lr;
      #pragma unroll
      for (int kk = 0; kk < 2; kk++)
        b[n][kk] = *(const bf16x8*)(Bp + rb * 128 + (((kk * 4 + lk) ^ (rb & 7)) * 16));
    }
    __builtin_amdgcn_s_setprio(1);
    #pragma unroll
    for (int kk = 0; kk < 2; kk++)
      #pragma unroll
      for (int m = 0; m < 4; m++)
        #pragma unroll
        for (int n = 0; n < 4; n++)
          acc[m][n] = __builtin_amdgcn_mfma_f32_16x16x32_bf16(a[m][kk], b[n][kk], acc[m][n], 0, 0, 0);
    __builtin_amdgcn_s_setprio(0);
    asm volatile("s_waitcnt vmcnt(0)" ::: "memory");
    __builtin_amdgcn_s_barrier();
    cur ^= 1;
  }
  #pragma unroll
  for (int m = 0; m < 4; m++)
    #pragma unroll
    for (int n = 0; n < 4; n++)
      #pragma unroll
      for (int j = 0; j < 4; j++) {
        int row = row0 + wr * 64 + m * 16 + lk * 4 + j;
        int col = col0 + wc * 64 + n * 16 + lr;
        C[(size_t)row * NM + col] = acc[m][n][j];
      }
}

// ---------------- MFMA attention + fused GroupNorm partial stats (o: bf16) ----------------
__global__ __launch_bounds__(256) void k_attn(const unsigned short* __restrict__ q,
    const unsigned short* __restrict__ kk, const unsigned short* __restrict__ vv,
    const float* __restrict__ cum, unsigned short* __restrict__ o,
    float* __restrict__ psum, float* __restrict__ psq) {
  int it = blockIdx.x, h = blockIdx.y, b = blockIdx.z;
  int i0 = it * 64;
  __shared__ unsigned short Qs[64 * 64];
  __shared__ unsigned short Ks[64 * 64];
  __shared__ unsigned short Ps[64 * 64];
  __shared__ unsigned short Vs[64 * 66];
  __shared__ float ci[64], cj[64];
  __shared__ int jlo_s;
  int tid = threadIdx.x;
  int w = tid >> 6, lane = tid & 63;
  int cl = lane & 15, hi = lane >> 4;
  const size_t hb = (size_t)b * NS * NDI + (size_t)h * ND;
  const float* cumh = cum + (size_t)(b * NH + h) * NS;

  #pragma unroll
  for (int lp = 0; lp < 2; lp++) {
    int idx = tid + lp * 256;
    int r = idx >> 3, cb = (idx & 7) * 16;
    uint4 t = *(const uint4*)(q + hb + (size_t)(i0 + r) * NDI + (cb >> 1));
    *(uint4*)((char*)Qs + r * 128 + (cb ^ ((r & 7) << 4))) = t;
  }
  if (tid < 64) ci[tid] = cumh[i0 + tid];
  if (tid < 64) {
    int jt = tid;
    bool ok = (jt <= it) && (cumh[i0] - cumh[jt * 64 + 63] >= -60.f);
    unsigned long long mask = __ballot(ok);
    if (tid == 0) jlo_s = (int)__builtin_ctzll(mask);
  }
  __syncthreads();
  int jlo = jlo_s;

  int arow = w * 16 + cl;
  int xr = (cl & 7) << 4;
  const char* Qb = (const char*)Qs + arow * 128;
  const char* Pb = (const char*)Ps + arow * 128;
  f32x4 acco[4] = {};

  for (int jt = jlo; jt <= it; jt++) {
    int j0 = jt * 64;
    __syncthreads();
    if (tid < 64) cj[tid] = cumh[j0 + tid];
    __syncthreads();
    #pragma unroll
    for (int lp = 0; lp < 2; lp++) {
      int idx = tid + lp * 256;
      int r = idx >> 3, cb = (idx & 7) * 16;
      uint4 t = *(const uint4*)(kk + hb + (size_t)(j0 + r) * NDI + (cb >> 1));
      *(uint4*)((char*)Ks + r * 128 + (cb ^ ((r & 7) << 4))) = t;
      uint4 tv = *(const uint4*)(vv + hb + (size_t)(j0 + r) * NDI + (cb >> 1));
      unsigned int uv[4]; *(uint4*)uv = tv;
      unsigned int* vd = (unsigned int*)(Vs + r * 66 + (cb >> 1));
      vd[0] = uv[0]; vd[1] = uv[1]; vd[2] = uv[2]; vd[3] = uv[3];
    }
    __syncthreads();
    bf16x8 a0 = *(const bf16x8*)(Qb + ((hi * 16) ^ xr));
    bf16x8 a1 = *(const bf16x8*)(Qb + ((64 + hi * 16) ^ xr));
    f32x4 accs[4] = {};
    #pragma unroll
    for (int jtile = 0; jtile < 4; jtile++) {
      const char* Kb = (const char*)Ks + (jtile * 16 + cl) * 128;
      bf16x8 b0 = *(const bf16x8*)(Kb + ((hi * 16) ^ xr));
      bf16x8 b1 = *(const bf16x8*)(Kb + ((64 + hi * 16) ^ xr));
      accs[jtile] = __builtin_amdgcn_mfma_f32_16x16x32_bf16(a0, b0, accs[jtile], 0, 0, 0);
      accs[jtile] = __builtin_amdgcn_mfma_f32_16x16x32_bf16(a1, b1, accs[jtile], 0, 0, 0);
    }
    #pragma unroll
    for (int jtile = 0; jtile < 4; jtile++) {
      #pragma unroll
      for (int reg = 0; reg < 4; reg++) {
        int irl = w * 16 + hi * 4 + reg;
        int jl = jtile * 16 + cl;
        float dec = ((j0 + jl) <= (i0 + irl)) ? __expf(ci[irl] - cj[jl]) : 0.f;
        float pv = accs[jtile][reg] * dec;
        *(unsigned short*)((char*)Ps + irl * 128 + ((2 * jl) ^ ((irl & 7) << 4))) = f2bf(pv);
      }
    }
    __syncthreads();
    #pragma unroll
    for (int kk2 = 0; kk2 < 2; kk2++) {
      bf16x8 pa = *(const bf16x8*)(Pb + ((kk2 * 64 + hi * 16) ^ xr));
      #pragma unroll
      for (int dt = 0; dt < 4; dt++) {
        bf16x8 vb;
        #pragma unroll
        for (int e = 0; e < 8; e++)
          vb[e] = (short)Vs[(kk2 * 32 + hi * 8 + e) * 66 + dt * 16 + cl];
        acco[dt] = __builtin_amdgcn_mfma_f32_16x16x32_bf16(pa, vb, acco[dt], 0, 0, 0);
      }
    }
  }
  #pragma unroll
  for (int dt = 0; dt < 4; dt++) {
    #pragma unroll
    for (int reg = 0; reg < 4; reg++) {
      int row = i0 + w * 16 + hi * 4 + reg;
      o[hb + (size_t)row * NDI + dt * 16 + cl] = f2bf(acco[dt][reg]);
    }
  }
  __syncthreads();
  float* ls = (float*)Ps;
  float* lq = ls + 256;
  float sm = 0.f, sq = 0.f;
  #pragma unroll
  for (int dt = 0; dt < 4; dt++)
    #pragma unroll
    for (int reg = 0; reg < 4; reg++) { float t2 = acco[dt][reg]; sm += t2; sq += t2 * t2; }
  ls[tid] = sm; lq[tid] = sq;
  __syncthreads();
  for (int off = 128; off > 0; off >>= 1) {
    if (tid < off) { ls[tid] += ls[tid + off]; lq[tid] += lq[tid + off]; }
    __syncthreads();
  }
  if (tid == 0) {
    atomicAdd(&psum[b * NH + h], ls[0]);
    atomicAdd(&psq[b * NH + h], lq[0]);
  }
}

// ---------------- u = (groupnorm(o)*w+b)*gate, bf16 out (stats inline) ----------------
__global__ __launch_bounds__(256) void k_gate(const unsigned short* __restrict__ o,
    const unsigned short* __restrict__ gsig, const float* __restrict__ psum,
    const float* __restrict__ psq, const float* __restrict__ gnw,
    const float* __restrict__ gnb, unsigned short* __restrict__ u) {
  int idx4 = blockIdx.x * 256 + threadIdx.x;
  size_t base = (size_t)idx4 * 4;
  int c = (int)(base & (NDI - 1));
  int row = (int)(base >> 10);
  int b = row >> 11;
  int h = c >> 6;
  int g = b * NH + h;
  float n = (float)(NS * ND);
  float mean = psum[g] / n;
  float var = psq[g] / n - mean * mean;
  float rstd = rsqrtf(var + 1e-5f);
  ushort4 ov = *(const ushort4*)(o + base);
  ushort4 gv = *(const ushort4*)(gsig + base);
  float4 w4 = *(const float4*)(gnw + c);
  float4 b4 = *(const float4*)(gnb + c);
  unsigned short r[4];
  r[0] = f2bf(((bf2f(ov.x) - mean) * rstd * w4.x + b4.x) * bf2f(gv.x));
  r[1] = f2bf(((bf2f(ov.y) - mean) * rstd * w4.y + b4.y) * bf2f(gv.y));
  r[2] = f2bf(((bf2f(ov.z) - mean) * rstd * w4.z + b4.z) * bf2f(gv.z));
  r[3] = f2bf(((bf2f(ov.w) - mean) * rstd * w4.w + b4.w) * bf2f(gv.w));
  *(ushort4*)(u + base) = *(const ushort4*)r;
}

extern "C" void kernel_launch(void* const* d_in, const int* in_sizes, int n_in,
                              void* d_out, int out_size, void* d_ws, size_t ws_size,
                              hipStream_t stream) {
  const float* x   = (const float*)d_in[0];
  const float* Wq  = (const float*)d_in[1];
  const float* Wk  = (const float*)d_in[2];
  const float* Wv  = (const float*)d_in[3];
  const float* Wg  = (const float*)d_in[4];
  const float* Wa  = (const float*)d_in[5];
  const float* ba  = (const float*)d_in[6];
  const float* Wo  = (const float*)d_in[7];
  const float* gnw = (const float*)d_in[8];
  const float* gnb = (const float*)d_in[9];
  float* out = (float*)d_out;

  const size_t NTOK = (size_t)NB * NS;        // 4096
  char* p = (char*)d_ws;
  float* la  = (float*)p;                 p += (size_t)NB * NH * NS * 4;  // 256 KB
  float* cum = (float*)p;                 p += (size_t)NB * NH * NS * 4;
  float* psum = (float*)p;                p += 32 * 4;
  float* psq  = (float*)p;                p += 32 * 4;
  p = (char*)(((uintptr_t)p + 255) & ~(uintptr_t)255);
  unsigned short* xb    = (unsigned short*)p; p += NTOK * NM * 2;          // 8 MB
  unsigned short* Wcat5 = (unsigned short*)p; p += (size_t)4224 * NM * 2;  // 8.25 MB
  unsigned short* wto   = (unsigned short*)p; p += (size_t)NDI * NM * 2;
  unsigned short* q  = (unsigned short*)p;  p += NTOK * NDI * 2;
  unsigned short* k  = (unsigned short*)p;  p += NTOK * NDI * 2;
  unsigned short* v  = (unsigned short*)p;  p += NTOK * NDI * 2;
  unsigned short* g  = (unsigned short*)p;  p += NTOK * NDI * 2;
  unsigned short* u  = (unsigned short*)p;  p += NTOK * NDI * 2;
  unsigned short* o  = (unsigned short*)p;  p += NTOK * NDI * 2;

  unsigned short* wtq = Wcat5;
  unsigned short* wtk = Wcat5 + (size_t)NM * NDI;
  unsigned short* wtv = Wcat5 + (size_t)2 * NM * NDI;
  unsigned short* wtg = Wcat5 + (size_t)3 * NM * NDI;
  unsigned short* wa_pad = Wcat5 + (size_t)4 * NM * NDI;   // rows 4096..4223

  k_prep   <<<dim3(7680), 256, 0, stream>>>(x, Wq, Wk, Wv, Wg, Wo, Wa,
                                            xb, wtq, wtk, wtv, wtg, wto, wa_pad);
  k_proj2  <<<dim3(1056), 256, 0, stream>>>(xb, Wcat5, ba, q, k, v, g, la);
  k_cumsum <<<dim3(NB * NH), 256, 0, stream>>>(la, cum, psum, psq);
  k_attn   <<<dim3(32, NH, NB), 256, 0, stream>>>(q, k, v, cum, o, psum, psq);
  k_gate   <<<dim3(4096), 256, 0, stream>>>(o, g, psum, psq, gnw, gnb, u);
  k_out2   <<<dim3(256), 256, 0, stream>>>(u, wto, out);
}

// Round 10
// 127.543 us; speedup vs baseline: 1.1924x; 1.1924x over previous
//
#include <hip/hip_runtime.h>
#include <math.h>
#include <stdint.h>

typedef __attribute__((ext_vector_type(4))) float f32x4;
typedef __attribute__((ext_vector_type(8))) short bf16x8;

constexpr int NB = 2;       // B
constexpr int NS = 2048;    // S
constexpr int NM = 1024;    // D_MODEL
constexpr int NH = 16;      // H
constexpr int ND = 64;      // D
constexpr int NDI = 1024;   // H*D

__device__ __forceinline__ float bf2f(unsigned short u) {
  uint32_t x = ((uint32_t)u) << 16; float f; __builtin_memcpy(&f, &x, 4); return f;
}
__device__ __forceinline__ unsigned short f2bf(float f) {
  uint32_t x; __builtin_memcpy(&x, &f, 4);
  x += 0x7FFFu + ((x >> 16) & 1u);            // RNE (finite values)
  return (unsigned short)(x >> 16);
}

// ---------------- fused preprocessing: cast x, transpose-cast 5 W, pad Wa ----------------
__global__ __launch_bounds__(256) void k_prep(const float* __restrict__ x,
    const float* __restrict__ w0, const float* __restrict__ w1,
    const float* __restrict__ w2, const float* __restrict__ w3,
    const float* __restrict__ w4, const float* __restrict__ Wa,
    unsigned short* __restrict__ xb,
    unsigned short* __restrict__ t0, unsigned short* __restrict__ t1,
    unsigned short* __restrict__ t2, unsigned short* __restrict__ t3,
    unsigned short* __restrict__ t4, unsigned short* __restrict__ wa_pad) {
  int bid = blockIdx.x;
  if (bid < 2048) {                            // ---- cast x ----
    int i = bid * 256 + threadIdx.x;
    const float4* p = (const float4*)(x + (size_t)i * 8);
    float4 a = p[0], b = p[1];
    unsigned short r[8] = {f2bf(a.x), f2bf(a.y), f2bf(a.z), f2bf(a.w),
                           f2bf(b.x), f2bf(b.y), f2bf(b.z), f2bf(b.w)};
    *(uint4*)(xb + (size_t)i * 8) = *(const uint4*)r;
  } else if (bid < 7168) {                     // ---- castT5 ----
    __shared__ float tile[32][33];
    int w = bid - 2048;
    int z = w >> 10, within = w & 1023;
    const float* src = z == 0 ? w0 : z == 1 ? w1 : z == 2 ? w2 : z == 3 ? w3 : w4;
    unsigned short* dst = z == 0 ? t0 : z == 1 ? t1 : z == 2 ? t2 : z == 3 ? t3 : t4;
    int c0 = (within & 31) * 32, r0 = (within >> 5) * 32;
    int tx = threadIdx.x & 31, ty = threadIdx.x >> 5;
    #pragma unroll
    for (int i = 0; i < 4; i++)
      tile[ty + i * 8][tx] = src[(size_t)(r0 + ty + i * 8) * 1024 + c0 + tx];
    __syncthreads();
    #pragma unroll
    for (int i = 0; i < 4; i++)
      dst[(size_t)(c0 + ty + i * 8) * 1024 + r0 + tx] = f2bf(tile[tx][ty + i * 8]);
  } else {                                     // ---- wa_pad ----
    int idx = (bid - 7168) * 256 + threadIdx.x;
    int h = idx >> 10, k2 = idx & 1023;
    wa_pad[idx] = (h < 16) ? f2bf(Wa[k2 * 16 + h]) : (unsigned short)0;
  }
}

// ---------------- la partial GEMM: K-split by 4 ----------------
__global__ __launch_bounds__(256) void k_la_gemm(const unsigned short* __restrict__ xb,
    const unsigned short* __restrict__ wa_pad, float* __restrict__ la4) {
  __shared__ unsigned short As[128 * 32];
  __shared__ unsigned short Bs[128 * 32];
  int tid = threadIdx.x;
  int row0 = blockIdx.y * 128;
  int kbeg = blockIdx.x * 256;
  float* Cp = la4 + (size_t)blockIdx.x * (32 * 2048);
  int w = tid >> 6, l = tid & 63;
  int wr = w >> 1, wc = w & 1;
  int lr = l & 15, lk = l >> 4;
  f32x4 acc[4] = {};
  for (int k0 = kbeg; k0 < kbeg + 256; k0 += 32) {
    __syncthreads();
    #pragma unroll
    for (int i = 0; i < 2; i++) {
      int idx = tid + i * 256;
      int r = idx >> 2, c = idx & 3;
      int cs = c ^ ((r >> 1) & 3);
      const unsigned short* srcA = xb + (size_t)(row0 + r) * NM + k0 + cs * 8;
      const unsigned short* srcB = wa_pad + (size_t)r * NM + k0 + cs * 8;
      __builtin_amdgcn_global_load_lds(
          (const __attribute__((address_space(1))) void*)srcA,
          (__attribute__((address_space(3))) void*)((char*)As + (w * 64 + i * 256) * 16),
          16, 0, 0);
      __builtin_amdgcn_global_load_lds(
          (const __attribute__((address_space(1))) void*)srcB,
          (__attribute__((address_space(3))) void*)((char*)Bs + (w * 64 + i * 256) * 16),
          16, 0, 0);
    }
    __syncthreads();
    if (wc == 0) {
      bf16x8 b = *(const bf16x8*)&Bs[lr * 32 + (lk ^ ((lr >> 1) & 3)) * 8];
      #pragma unroll
      for (int m = 0; m < 4; m++) {
        int ra = wr * 64 + m * 16 + lr;
        bf16x8 a = *(const bf16x8*)&As[ra * 32 + (lk ^ ((ra >> 1) & 3)) * 8];
        acc[m] = __builtin_amdgcn_mfma_f32_16x16x32_bf16(a, b, acc[m], 0, 0, 0);
      }
    }
  }
  if (wc == 0) {
    #pragma unroll
    for (int m = 0; m < 4; m++) {
      #pragma unroll
      for (int j = 0; j < 4; j++) {
        int row = row0 + wr * 64 + m * 16 + lk * 4 + j;
        int bb = row >> 11, s = row & 2047;
        Cp[((size_t)(bb * 16 + lr)) * 2048 + s] = acc[m][j];
      }
    }
  }
}

// ---------------- cumsum: sum slices + bias, -softplus, scan; zero psum/psq ----------------
__global__ __launch_bounds__(256) void k_cumsum(const float* __restrict__ la4,
    const float* __restrict__ ba, float* __restrict__ cum,
    float* __restrict__ psum, float* __restrict__ psq) {
  int g = blockIdx.x;
  int h = g & 15;
  if (threadIdx.x == 0) { psum[g] = 0.f; psq[g] = 0.f; }
  float bah = ba[h];
  const float* p0 = la4 + (size_t)g * NS;
  float* out = cum + (size_t)g * NS;
  __shared__ float part[256];
  float v[8]; float sum = 0.f;
  int base = threadIdx.x * 8;
  #pragma unroll
  for (int i = 0; i < 8; i++) {
    int s = base + i;
    float z = p0[s] + p0[65536 + s] + p0[131072 + s] + p0[196608 + s] + bah;
    float sp = fmaxf(z, 0.f) + log1pf(expf(-fabsf(z)));
    v[i] = -sp; sum += v[i];
  }
  part[threadIdx.x] = sum;
  __syncthreads();
  for (int off = 1; off < 256; off <<= 1) {
    float add = (threadIdx.x >= off) ? part[threadIdx.x - off] : 0.f;
    __syncthreads();
    part[threadIdx.x] += add;
    __syncthreads();
  }
  float run = (threadIdx.x > 0) ? part[threadIdx.x - 1] : 0.f;
  #pragma unroll
  for (int i = 0; i < 8; i++) { run += v[i]; out[base + i] = run; }
}

// ======================================================================
// k_proj8: 256x256 tile, BK=64, 8 waves, 4-phase/K-tile per-phase
// barrier discipline. RACE FIX vs r9: s_barrier immediately after the
// vmcnt gate — vmcnt is PER-WAVE; the barrier is what proves ALL waves'
// cooperative staging landed before any wave reads the buffer.
// ======================================================================
#define LD8(base, r, kc) (*(const bf16x8*)((base) + (size_t)(r) * 128 + ((((kc)) ^ ((r) & 7)) * 16)))

__global__ __launch_bounds__(512, 1) void k_proj8(
    const unsigned short* __restrict__ A,
    const unsigned short* __restrict__ Wcat,
    unsigned short* __restrict__ q, unsigned short* __restrict__ k,
    unsigned short* __restrict__ v, unsigned short* __restrict__ g) {
  __shared__ unsigned short Ab[2][256 * 64];   // 64 KB
  __shared__ unsigned short Bb[2][256 * 64];   // 64 KB
  int tid = threadIdx.x;
  int bid = blockIdx.x;                        // 0..255
  int wg = (bid & 7) * 32 + (bid >> 3);        // XCD-bijective swizzle
  int bx = wg & 15, by = wg >> 4;
  int row0 = by * 256, col0 = bx * 256;
  int wid = tid >> 6, lane = tid & 63;
  int WR = wid >> 2, WC = wid & 3;             // 2M x 4N wave grid
  int lr = lane & 15, lk = lane >> 4;

  auto stage = [&](int kt, int bi) {
    #pragma unroll
    for (int i = 0; i < 4; i++) {
      int idx = tid + i * 512;                 // chunk 0..2047
      int r = idx >> 3, c = idx & 7;
      int cs = c ^ (r & 7);                    // pre-swizzled source (T2, rule 21)
      const unsigned short* srcA = A + (size_t)(row0 + r) * NM + kt * 64 + cs * 8;
      __builtin_amdgcn_global_load_lds(
          (const __attribute__((address_space(1))) void*)srcA,
          (__attribute__((address_space(3))) void*)((char*)&Ab[bi][0] + (wid * 64 + i * 512) * 16),
          16, 0, 0);
      const unsigned short* srcB = Wcat + (size_t)(col0 + r) * NM + kt * 64 + cs * 8;
      __builtin_amdgcn_global_load_lds(
          (const __attribute__((address_space(1))) void*)srcB,
          (__attribute__((address_space(3))) void*)((char*)&Bb[bi][0] + (wid * 64 + i * 512) * 16),
          16, 0, 0);
    }
  };

  stage(0, 0);
  stage(1, 1);

  f32x4 acc[8][4] = {};
  bf16x8 a[4][2], blo[2][2], bhi[2][2];

  for (int kt = 0; kt < 16; ++kt) {
    int bi = kt & 1;
    // ---- counted gate: MY stage(kt) loads landed; barrier: EVERYONE's did ----
    if (kt < 15) asm volatile("s_waitcnt vmcnt(8)" ::: "memory");
    else         asm volatile("s_waitcnt vmcnt(0)" ::: "memory");
    __builtin_amdgcn_sched_barrier(0);
    __builtin_amdgcn_s_barrier();              // RACE FIX (vmcnt is per-wave)
    const char* Ap = (const char*)&Ab[bi][0];
    const char* Bp = (const char*)&Bb[bi][0];

    // ======== ph0: 12 ds_reads (a m0-3, blo) ; MFMA Q00 ========
    #pragma unroll
    for (int m = 0; m < 4; m++) {
      int r = WR * 128 + m * 16 + lr;
      a[m][0] = LD8(Ap, r, lk); a[m][1] = LD8(Ap, r, lk + 4);
    }
    #pragma unroll
    for (int n = 0; n < 2; n++) {
      int r = WC * 64 + n * 16 + lr;
      blo[n][0] = LD8(Bp, r, lk); blo[n][1] = LD8(Bp, r, lk + 4);
    }
    asm volatile("s_waitcnt lgkmcnt(0)" ::: "memory");
    __builtin_amdgcn_sched_barrier(0);
    __builtin_amdgcn_s_setprio(1);
    #pragma unroll
    for (int kk = 0; kk < 2; kk++)
      #pragma unroll
      for (int m = 0; m < 4; m++)
        #pragma unroll
        for (int n = 0; n < 2; n++)
          acc[m][n] = __builtin_amdgcn_mfma_f32_16x16x32_bf16(a[m][kk], blo[n][kk], acc[m][n], 0, 0, 0);
    __builtin_amdgcn_s_setprio(0);
    __builtin_amdgcn_s_barrier();

    // ======== ph1: 4 ds_reads (bhi) ; MFMA Q01 ========
    #pragma unroll
    for (int n = 0; n < 2; n++) {
      int r = WC * 64 + (2 + n) * 16 + lr;
      bhi[n][0] = LD8(Bp, r, lk); bhi[n][1] = LD8(Bp, r, lk + 4);
    }
    asm volatile("s_waitcnt lgkmcnt(0)" ::: "memory");
    __builtin_amdgcn_sched_barrier(0);
    __builtin_amdgcn_s_setprio(1);
    #pragma unroll
    for (int kk = 0; kk < 2; kk++)
      #pragma unroll
      for (int m = 0; m < 4; m++)
        #pragma unroll
        for (int n = 0; n < 2; n++)
          acc[m][2 + n] = __builtin_amdgcn_mfma_f32_16x16x32_bf16(a[m][kk], bhi[n][kk], acc[m][2 + n], 0, 0, 0);
    __builtin_amdgcn_s_setprio(0);
    __builtin_amdgcn_s_barrier();

    // ======== ph2: 8 ds_reads (a -> m4-7) ; MFMA Q11 ========
    #pragma unroll
    for (int m = 0; m < 4; m++) {
      int r = WR * 128 + (4 + m) * 16 + lr;
      a[m][0] = LD8(Ap, r, lk); a[m][1] = LD8(Ap, r, lk + 4);
    }
    asm volatile("s_waitcnt lgkmcnt(0)" ::: "memory");
    __builtin_amdgcn_sched_barrier(0);
    __builtin_amdgcn_s_setprio(1);
    #pragma unroll
    for (int kk = 0; kk < 2; kk++)
      #pragma unroll
      for (int m = 0; m < 4; m++)
        #pragma unroll
        for (int n = 0; n < 2; n++)
          acc[4 + m][2 + n] = __builtin_amdgcn_mfma_f32_16x16x32_bf16(a[m][kk], bhi[n][kk], acc[4 + m][2 + n], 0, 0, 0);
    __builtin_amdgcn_s_setprio(0);
    __builtin_amdgcn_s_barrier();              // all waves done reading buf bi

    // ======== ph3: stage(kt+2) into freed buf ; MFMA Q10 (regs only) ========
    if (kt + 2 < 16) stage(kt + 2, bi);
    __builtin_amdgcn_s_setprio(1);
    #pragma unroll
    for (int kk = 0; kk < 2; kk++)
      #pragma unroll
      for (int m = 0; m < 4; m++)
        #pragma unroll
        for (int n = 0; n < 2; n++)
          acc[4 + m][n] = __builtin_amdgcn_mfma_f32_16x16x32_bf16(a[m][kk], blo[n][kk], acc[4 + m][n], 0, 0, 0);
    __builtin_amdgcn_s_setprio(0);
  }

  // epilogue: zone uniform per block (col0 is 256-aligned within 1024)
  #pragma unroll
  for (int m = 0; m < 8; m++) {
    #pragma unroll
    for (int n = 0; n < 4; n++) {
      int col = col0 + WC * 64 + n * 16 + lr;
      int zone = col >> 10;
      unsigned short* dst = zone == 0 ? q : zone == 1 ? k : zone == 2 ? v : g;
      int cb = col & 1023;
      #pragma unroll
      for (int j = 0; j < 4; j++) {
        int row = row0 + WR * 128 + m * 16 + lk * 4 + j;
        float val = acc[m][n][j];
        if (zone <= 1) val = val / (1.f + expf(-val));        // silu
        else if (zone == 3) val = 1.f / (1.f + expf(-val));   // sigmoid
        dst[(size_t)row * 1024 + cb] = f2bf(val);
      }
    }
  }
}

// ======================================================================
// k_out2: out = u @ Wo^T, 128x128 tile, BK=64 double-buffer, 2-phase.
// ======================================================================
__global__ __launch_bounds__(256) void k_out2(const unsigned short* __restrict__ A,
    const unsigned short* __restrict__ Bt, float* __restrict__ C) {
  __shared__ unsigned short As[2][128 * 64];
  __shared__ unsigned short Bs[2][128 * 64];
  int tid = threadIdx.x;
  int bid = blockIdx.x;                        // 0..255
  int wg = (bid & 7) * 32 + (bid >> 3);        // XCD-bijective swizzle
  int bx = wg & 7, by = wg >> 3;
  int row0 = by * 128, col0 = bx * 128;
  int w = tid >> 6, l = tid & 63;
  int wr = w >> 1, wc = w & 1;
  int lr = l & 15, lk = l >> 4;

  auto stage = [&](int t, int bi) {
    #pragma unroll
    for (int i = 0; i < 4; i++) {
      int idx = tid + i * 256;
      int r = idx >> 3, c = idx & 7;
      int cs = c ^ (r & 7);
      const unsigned short* srcA = A + (size_t)(row0 + r) * NM + t * 64 + cs * 8;
      __builtin_amdgcn_global_load_lds(
          (const __attribute__((address_space(1))) void*)srcA,
          (__attribute__((address_space(3))) void*)((char*)&As[bi][0] + idx * 16),
          16, 0, 0);
      const unsigned short* srcB = Bt + (size_t)(col0 + r) * NM + t * 64 + cs * 8;
      __builtin_amdgcn_global_load_lds(
          (const __attribute__((address_space(1))) void*)srcB,
          (__attribute__((address_space(3))) void*)((char*)&Bs[bi][0] + idx * 16),
          16, 0, 0);
    }
  };

  stage(0, 0);
  asm volatile("s_waitcnt vmcnt(0)" ::: "memory");
  __builtin_amdgcn_s_barrier();

  f32x4 acc[4][4] = {};
  int cur = 0;
  for (int t = 0; t < 16; ++t) {
    if (t < 15) stage(t + 1, cur ^ 1);
    const char* Ap = (const char*)&As[cur][0];
    const char* Bp = (const char*)&Bs[cur][0];
    bf16x8 a[4][2], b[4][2];
    #pragma unroll
    for (int m = 0; m < 4; m++) {
      int ra = wr * 64 + m * 16 + lr;
      #pragma unroll
      for (int kk = 0; kk < 2; kk++)
        a[m][kk] = *(const bf16x8*)(Ap + ra * 128 + (((kk * 4 + lk) ^ (ra & 7)) * 16));
    }
    #pragma unroll
    for (int n = 0; n < 4; n++) {
      int rb = wc * 64 + n * 16 + lr;
      #pragma unroll
      for (int kk = 0; kk < 2; kk++)
        b[n][kk] = *(const bf16x8*)(Bp + rb * 128 + (((kk * 4 + lk) ^ (rb & 7)) * 16));
    }
    __builtin_amdgcn_s_setprio(1);
    #pragma unroll
    for (int kk = 0; kk < 2; kk++)
      #pragma unroll
      for (int m = 0; m < 4; m++)
        #pragma unroll
        for (int n = 0; n < 4; n++)
          acc[m][n] = __builtin_amdgcn_mfma_f32_16x16x32_bf16(a[m][kk], b[n][kk], acc[m][n], 0, 0, 0);
    __builtin_amdgcn_s_setprio(0);
    asm volatile("s_waitcnt vmcnt(0)" ::: "memory");
    __builtin_amdgcn_s_barrier();
    cur ^= 1;
  }
  #pragma unroll
  for (int m = 0; m < 4; m++)
    #pragma unroll
    for (int n = 0; n < 4; n++)
      #pragma unroll
      for (int j = 0; j < 4; j++) {
        int row = row0 + wr * 64 + m * 16 + lk * 4 + j;
        int col = col0 + wc * 64 + n * 16 + lr;
        C[(size_t)row * NM + col] = acc[m][n][j];
      }
}

// ---------------- MFMA attention + fused GroupNorm partial stats (o: bf16) ----------------
__global__ __launch_bounds__(256) void k_attn(const unsigned short* __restrict__ q,
    const unsigned short* __restrict__ kk, const unsigned short* __restrict__ vv,
    const float* __restrict__ cum, unsigned short* __restrict__ o,
    float* __restrict__ psum, float* __restrict__ psq) {
  int it = blockIdx.x, h = blockIdx.y, b = blockIdx.z;
  int i0 = it * 64;
  __shared__ unsigned short Qs[64 * 64];
  __shared__ unsigned short Ks[64 * 64];
  __shared__ unsigned short Ps[64 * 64];
  __shared__ unsigned short Vs[64 * 66];
  __shared__ float ci[64], cj[64];
  __shared__ int jlo_s;
  int tid = threadIdx.x;
  int w = tid >> 6, lane = tid & 63;
  int cl = lane & 15, hi = lane >> 4;
  const size_t hb = (size_t)b * NS * NDI + (size_t)h * ND;
  const float* cumh = cum + (size_t)(b * NH + h) * NS;

  #pragma unroll
  for (int lp = 0; lp < 2; lp++) {
    int idx = tid + lp * 256;
    int r = idx >> 3, cb = (idx & 7) * 16;
    uint4 t = *(const uint4*)(q + hb + (size_t)(i0 + r) * NDI + (cb >> 1));
    *(uint4*)((char*)Qs + r * 128 + (cb ^ ((r & 7) << 4))) = t;
  }
  if (tid < 64) ci[tid] = cumh[i0 + tid];
  if (tid < 64) {
    int jt = tid;
    bool ok = (jt <= it) && (cumh[i0] - cumh[jt * 64 + 63] >= -60.f);
    unsigned long long mask = __ballot(ok);
    if (tid == 0) jlo_s = (int)__builtin_ctzll(mask);
  }
  __syncthreads();
  int jlo = jlo_s;

  int arow = w * 16 + cl;
  int xr = (cl & 7) << 4;
  const char* Qb = (const char*)Qs + arow * 128;
  const char* Pb = (const char*)Ps + arow * 128;
  f32x4 acco[4] = {};

  for (int jt = jlo; jt <= it; jt++) {
    int j0 = jt * 64;
    __syncthreads();
    if (tid < 64) cj[tid] = cumh[j0 + tid];
    __syncthreads();
    #pragma unroll
    for (int lp = 0; lp < 2; lp++) {
      int idx = tid + lp * 256;
      int r = idx >> 3, cb = (idx & 7) * 16;
      uint4 t = *(const uint4*)(kk + hb + (size_t)(j0 + r) * NDI + (cb >> 1));
      *(uint4*)((char*)Ks + r * 128 + (cb ^ ((r & 7) << 4))) = t;
      uint4 tv = *(const uint4*)(vv + hb + (size_t)(j0 + r) * NDI + (cb >> 1));
      unsigned int uv[4]; *(uint4*)uv = tv;
      unsigned int* vd = (unsigned int*)(Vs + r * 66 + (cb >> 1));
      vd[0] = uv[0]; vd[1] = uv[1]; vd[2] = uv[2]; vd[3] = uv[3];
    }
    __syncthreads();
    bf16x8 a0 = *(const bf16x8*)(Qb + ((hi * 16) ^ xr));
    bf16x8 a1 = *(const bf16x8*)(Qb + ((64 + hi * 16) ^ xr));
    f32x4 accs[4] = {};
    #pragma unroll
    for (int jtile = 0; jtile < 4; jtile++) {
      const char* Kb = (const char*)Ks + (jtile * 16 + cl) * 128;
      bf16x8 b0 = *(const bf16x8*)(Kb + ((hi * 16) ^ xr));
      bf16x8 b1 = *(const bf16x8*)(Kb + ((64 + hi * 16) ^ xr));
      accs[jtile] = __builtin_amdgcn_mfma_f32_16x16x32_bf16(a0, b0, accs[jtile], 0, 0, 0);
      accs[jtile] = __builtin_amdgcn_mfma_f32_16x16x32_bf16(a1, b1, accs[jtile], 0, 0, 0);
    }
    #pragma unroll
    for (int jtile = 0; jtile < 4; jtile++) {
      #pragma unroll
      for (int reg = 0; reg < 4; reg++) {
        int irl = w * 16 + hi * 4 + reg;
        int jl = jtile * 16 + cl;
        float dec = ((j0 + jl) <= (i0 + irl)) ? __expf(ci[irl] - cj[jl]) : 0.f;
        float pv = accs[jtile][reg] * dec;
        *(unsigned short*)((char*)Ps + irl * 128 + ((2 * jl) ^ ((irl & 7) << 4))) = f2bf(pv);
      }
    }
    __syncthreads();
    #pragma unroll
    for (int kk2 = 0; kk2 < 2; kk2++) {
      bf16x8 pa = *(const bf16x8*)(Pb + ((kk2 * 64 + hi * 16) ^ xr));
      #pragma unroll
      for (int dt = 0; dt < 4; dt++) {
        bf16x8 vb;
        #pragma unroll
        for (int e = 0; e < 8; e++)
          vb[e] = (short)Vs[(kk2 * 32 + hi * 8 + e) * 66 + dt * 16 + cl];
        acco[dt] = __builtin_amdgcn_mfma_f32_16x16x32_bf16(pa, vb, acco[dt], 0, 0, 0);
      }
    }
  }
  #pragma unroll
  for (int dt = 0; dt < 4; dt++) {
    #pragma unroll
    for (int reg = 0; reg < 4; reg++) {
      int row = i0 + w * 16 + hi * 4 + reg;
      o[hb + (size_t)row * NDI + dt * 16 + cl] = f2bf(acco[dt][reg]);
    }
  }
  __syncthreads();
  float* ls = (float*)Ps;
  float* lq = ls + 256;
  float sm = 0.f, sq = 0.f;
  #pragma unroll
  for (int dt = 0; dt < 4; dt++)
    #pragma unroll
    for (int reg = 0; reg < 4; reg++) { float t2 = acco[dt][reg]; sm += t2; sq += t2 * t2; }
  ls[tid] = sm; lq[tid] = sq;
  __syncthreads();
  for (int off = 128; off > 0; off >>= 1) {
    if (tid < off) { ls[tid] += ls[tid + off]; lq[tid] += lq[tid + off]; }
    __syncthreads();
  }
  if (tid == 0) {
    atomicAdd(&psum[b * NH + h], ls[0]);
    atomicAdd(&psq[b * NH + h], lq[0]);
  }
}

// ---------------- u = (groupnorm(o)*w+b)*gate, bf16 out (stats inline) ----------------
__global__ __launch_bounds__(256) void k_gate(const unsigned short* __restrict__ o,
    const unsigned short* __restrict__ gsig, const float* __restrict__ psum,
    const float* __restrict__ psq, const float* __restrict__ gnw,
    const float* __restrict__ gnb, unsigned short* __restrict__ u) {
  int idx4 = blockIdx.x * 256 + threadIdx.x;
  size_t base = (size_t)idx4 * 4;
  int c = (int)(base & (NDI - 1));
  int row = (int)(base >> 10);
  int b = row >> 11;
  int h = c >> 6;
  int g = b * NH + h;
  float n = (float)(NS * ND);
  float mean = psum[g] / n;
  float var = psq[g] / n - mean * mean;
  float rstd = rsqrtf(var + 1e-5f);
  ushort4 ov = *(const ushort4*)(o + base);
  ushort4 gv = *(const ushort4*)(gsig + base);
  float4 w4 = *(const float4*)(gnw + c);
  float4 b4 = *(const float4*)(gnb + c);
  unsigned short r[4];
  r[0] = f2bf(((bf2f(ov.x) - mean) * rstd * w4.x + b4.x) * bf2f(gv.x));
  r[1] = f2bf(((bf2f(ov.y) - mean) * rstd * w4.y + b4.y) * bf2f(gv.y));
  r[2] = f2bf(((bf2f(ov.z) - mean) * rstd * w4.z + b4.z) * bf2f(gv.z));
  r[3] = f2bf(((bf2f(ov.w) - mean) * rstd * w4.w + b4.w) * bf2f(gv.w));
  *(ushort4*)(u + base) = *(const ushort4*)r;
}

extern "C" void kernel_launch(void* const* d_in, const int* in_sizes, int n_in,
                              void* d_out, int out_size, void* d_ws, size_t ws_size,
                              hipStream_t stream) {
  const float* x   = (const float*)d_in[0];
  const float* Wq  = (const float*)d_in[1];
  const float* Wk  = (const float*)d_in[2];
  const float* Wv  = (const float*)d_in[3];
  const float* Wg  = (const float*)d_in[4];
  const float* Wa  = (const float*)d_in[5];
  const float* ba  = (const float*)d_in[6];
  const float* Wo  = (const float*)d_in[7];
  const float* gnw = (const float*)d_in[8];
  const float* gnb = (const float*)d_in[9];
  float* out = (float*)d_out;

  const size_t NTOK = (size_t)NB * NS;        // 4096
  char* p = (char*)d_ws;
  float* la4 = (float*)p;                 p += (size_t)4 * 32 * NS * 4;   // 1 MB
  float* cum = (float*)p;                 p += (size_t)NB * NH * NS * 4;
  float* psum = (float*)p;                p += 32 * 4;
  float* psq  = (float*)p;                p += 32 * 4;
  p = (char*)(((uintptr_t)p + 255) & ~(uintptr_t)255);
  unsigned short* xb   = (unsigned short*)p; p += NTOK * NM * 2;        // 8 MB
  unsigned short* Wcat = (unsigned short*)p; p += (size_t)4 * NM * NDI * 2; // 8 MB
  unsigned short* wto  = (unsigned short*)p; p += (size_t)NDI * NM * 2;
  unsigned short* wa_pad = (unsigned short*)p; p += (size_t)128 * NM * 2;
  unsigned short* q  = (unsigned short*)p;  p += NTOK * NDI * 2;
  unsigned short* k  = (unsigned short*)p;  p += NTOK * NDI * 2;
  unsigned short* v  = (unsigned short*)p;  p += NTOK * NDI * 2;
  unsigned short* g  = (unsigned short*)p;  p += NTOK * NDI * 2;
  unsigned short* u  = (unsigned short*)p;  p += NTOK * NDI * 2;
  unsigned short* o  = (unsigned short*)p;  p += NTOK * NDI * 2;

  unsigned short* wtq = Wcat;
  unsigned short* wtk = Wcat + (size_t)NM * NDI;
  unsigned short* wtv = Wcat + (size_t)2 * NM * NDI;
  unsigned short* wtg = Wcat + (size_t)3 * NM * NDI;

  k_prep    <<<dim3(7680), 256, 0, stream>>>(x, Wq, Wk, Wv, Wg, Wo, Wa,
                                             xb, wtq, wtk, wtv, wtg, wto, wa_pad);
  k_la_gemm <<<dim3(4, 32), 256, 0, stream>>>(xb, wa_pad, la4);
  k_cumsum  <<<dim3(NB * NH), 256, 0, stream>>>(la4, ba, cum, psum, psq);
  k_proj8   <<<dim3(256), 512, 0, stream>>>(xb, Wcat, q, k, v, g);
  k_attn    <<<dim3(32, NH, NB), 256, 0, stream>>>(q, k, v, cum, o, psum, psq);
  k_gate    <<<dim3(4096), 256, 0, stream>>>(o, g, psum, psq, gnw, gnb, u);
  k_out2    <<<dim3(256), 256, 0, stream>>>(u, wto, out);
}

// Round 11
// 123.570 us; speedup vs baseline: 1.2307x; 1.0322x over previous
//
#include <hip/hip_runtime.h>
#include <math.h>
#include <stdint.h>

typedef __attribute__((ext_vector_type(4))) float f32x4;
typedef __attribute__((ext_vector_type(8))) short bf16x8;

constexpr int NB = 2;       // B
constexpr int NS = 2048;    // S
constexpr int NM = 1024;    // D_MODEL
constexpr int NH = 16;      // H
constexpr int ND = 64;      // D
constexpr int NDI = 1024;   // H*D

__device__ __forceinline__ float bf2f(unsigned short u) {
  uint32_t x = ((uint32_t)u) << 16; float f; __builtin_memcpy(&f, &x, 4); return f;
}
__device__ __forceinline__ unsigned short f2bf(float f) {
  uint32_t x; __builtin_memcpy(&x, &f, 4);
  x += 0x7FFFu + ((x >> 16) & 1u);            // RNE (finite values)
  return (unsigned short)(x >> 16);
}

// ---------------- fused preprocessing: cast x, transpose-cast 5 W, pad Wa ----------------
__global__ __launch_bounds__(256) void k_prep(const float* __restrict__ x,
    const float* __restrict__ w0, const float* __restrict__ w1,
    const float* __restrict__ w2, const float* __restrict__ w3,
    const float* __restrict__ w4, const float* __restrict__ Wa,
    unsigned short* __restrict__ xb,
    unsigned short* __restrict__ t0, unsigned short* __restrict__ t1,
    unsigned short* __restrict__ t2, unsigned short* __restrict__ t3,
    unsigned short* __restrict__ t4, unsigned short* __restrict__ wa_pad) {
  int bid = blockIdx.x;
  if (bid < 2048) {                            // ---- cast x ----
    int i = bid * 256 + threadIdx.x;
    const float4* p = (const float4*)(x + (size_t)i * 8);
    float4 a = p[0], b = p[1];
    unsigned short r[8] = {f2bf(a.x), f2bf(a.y), f2bf(a.z), f2bf(a.w),
                           f2bf(b.x), f2bf(b.y), f2bf(b.z), f2bf(b.w)};
    *(uint4*)(xb + (size_t)i * 8) = *(const uint4*)r;
  } else if (bid < 7168) {                     // ---- castT5 ----
    __shared__ float tile[32][33];
    int w = bid - 2048;
    int z = w >> 10, within = w & 1023;
    const float* src = z == 0 ? w0 : z == 1 ? w1 : z == 2 ? w2 : z == 3 ? w3 : w4;
    unsigned short* dst = z == 0 ? t0 : z == 1 ? t1 : z == 2 ? t2 : z == 3 ? t3 : t4;
    int c0 = (within & 31) * 32, r0 = (within >> 5) * 32;
    int tx = threadIdx.x & 31, ty = threadIdx.x >> 5;
    #pragma unroll
    for (int i = 0; i < 4; i++)
      tile[ty + i * 8][tx] = src[(size_t)(r0 + ty + i * 8) * 1024 + c0 + tx];
    __syncthreads();
    #pragma unroll
    for (int i = 0; i < 4; i++)
      dst[(size_t)(c0 + ty + i * 8) * 1024 + r0 + tx] = f2bf(tile[tx][ty + i * 8]);
  } else {                                     // ---- wa_pad ----
    int idx = (bid - 7168) * 256 + threadIdx.x;
    int h = idx >> 10, k2 = idx & 1023;
    wa_pad[idx] = (h < 16) ? f2bf(Wa[k2 * 16 + h]) : (unsigned short)0;
  }
}

// ---------------- la partial GEMM: K-split by 4 ----------------
__global__ __launch_bounds__(256) void k_la_gemm(const unsigned short* __restrict__ xb,
    const unsigned short* __restrict__ wa_pad, float* __restrict__ la4) {
  __shared__ unsigned short As[128 * 32];
  __shared__ unsigned short Bs[128 * 32];
  int tid = threadIdx.x;
  int row0 = blockIdx.y * 128;
  int kbeg = blockIdx.x * 256;
  float* Cp = la4 + (size_t)blockIdx.x * (32 * 2048);
  int w = tid >> 6, l = tid & 63;
  int wr = w >> 1, wc = w & 1;
  int lr = l & 15, lk = l >> 4;
  f32x4 acc[4] = {};
  for (int k0 = kbeg; k0 < kbeg + 256; k0 += 32) {
    __syncthreads();
    #pragma unroll
    for (int i = 0; i < 2; i++) {
      int idx = tid + i * 256;
      int r = idx >> 2, c = idx & 3;
      int cs = c ^ ((r >> 1) & 3);
      const unsigned short* srcA = xb + (size_t)(row0 + r) * NM + k0 + cs * 8;
      const unsigned short* srcB = wa_pad + (size_t)r * NM + k0 + cs * 8;
      __builtin_amdgcn_global_load_lds(
          (const __attribute__((address_space(1))) void*)srcA,
          (__attribute__((address_space(3))) void*)((char*)As + (w * 64 + i * 256) * 16),
          16, 0, 0);
      __builtin_amdgcn_global_load_lds(
          (const __attribute__((address_space(1))) void*)srcB,
          (__attribute__((address_space(3))) void*)((char*)Bs + (w * 64 + i * 256) * 16),
          16, 0, 0);
    }
    __syncthreads();
    if (wc == 0) {
      bf16x8 b = *(const bf16x8*)&Bs[lr * 32 + (lk ^ ((lr >> 1) & 3)) * 8];
      #pragma unroll
      for (int m = 0; m < 4; m++) {
        int ra = wr * 64 + m * 16 + lr;
        bf16x8 a = *(const bf16x8*)&As[ra * 32 + (lk ^ ((ra >> 1) & 3)) * 8];
        acc[m] = __builtin_amdgcn_mfma_f32_16x16x32_bf16(a, b, acc[m], 0, 0, 0);
      }
    }
  }
  if (wc == 0) {
    #pragma unroll
    for (int m = 0; m < 4; m++) {
      #pragma unroll
      for (int j = 0; j < 4; j++) {
        int row = row0 + wr * 64 + m * 16 + lk * 4 + j;
        int bb = row >> 11, s = row & 2047;
        Cp[((size_t)(bb * 16 + lr)) * 2048 + s] = acc[m][j];
      }
    }
  }
}

// ---------------- cumsum: sum slices + bias, -softplus, scan; zero psum/psq ----------------
__global__ __launch_bounds__(256) void k_cumsum(const float* __restrict__ la4,
    const float* __restrict__ ba, float* __restrict__ cum,
    float* __restrict__ psum, float* __restrict__ psq) {
  int g = blockIdx.x;
  int h = g & 15;
  if (threadIdx.x == 0) { psum[g] = 0.f; psq[g] = 0.f; }
  float bah = ba[h];
  const float* p0 = la4 + (size_t)g * NS;
  float* out = cum + (size_t)g * NS;
  __shared__ float part[256];
  float v[8]; float sum = 0.f;
  int base = threadIdx.x * 8;
  #pragma unroll
  for (int i = 0; i < 8; i++) {
    int s = base + i;
    float z = p0[s] + p0[65536 + s] + p0[131072 + s] + p0[196608 + s] + bah;
    float sp = fmaxf(z, 0.f) + log1pf(expf(-fabsf(z)));
    v[i] = -sp; sum += v[i];
  }
  part[threadIdx.x] = sum;
  __syncthreads();
  for (int off = 1; off < 256; off <<= 1) {
    float add = (threadIdx.x >= off) ? part[threadIdx.x - off] : 0.f;
    __syncthreads();
    part[threadIdx.x] += add;
    __syncthreads();
  }
  float run = (threadIdx.x > 0) ? part[threadIdx.x - 1] : 0.f;
  #pragma unroll
  for (int i = 0; i < 8; i++) { run += v[i]; out[base + i] = run; }
}

// ======================================================================
// k_proj8 (r4-proven): fused q|k|v|g, 256x256 tile, BK=64, 8 waves,
// counted-vmcnt double buffer, source-swizzled LDS, setprio.
// Structural ceiling ~670 TF for 2-phase at this K (3 schedule rewrites
// confirmed no gain) — accepted.
// ======================================================================
__global__ __launch_bounds__(512, 2) void k_proj8(
    const unsigned short* __restrict__ A,
    const unsigned short* __restrict__ Wcat,
    unsigned short* __restrict__ q, unsigned short* __restrict__ k,
    unsigned short* __restrict__ v, unsigned short* __restrict__ g) {
  __shared__ unsigned short Ab[2][256 * 64];   // 64 KB
  __shared__ unsigned short Bb[2][256 * 64];   // 64 KB
  int tid = threadIdx.x;
  int bid = blockIdx.x;                        // 0..255
  int wg = (bid & 7) * 32 + (bid >> 3);        // XCD-bijective swizzle
  int bx = wg & 15, by = wg >> 4;
  int row0 = by * 256, col0 = bx * 256;
  int wid = tid >> 6, lane = tid & 63;
  int WR = wid >> 2, WC = wid & 3;             // 2M x 4N wave grid
  int lr = lane & 15, lk = lane >> 4;

  auto stage = [&](int kt, int bi) {
    #pragma unroll
    for (int i = 0; i < 4; i++) {
      int idx = tid + i * 512;                 // chunk 0..2047
      int r = idx >> 3, c = idx & 7;
      int cs = c ^ (r & 7);                    // pre-swizzled source (T2, rule 21)
      const unsigned short* srcA = A + (size_t)(row0 + r) * NM + kt * 64 + cs * 8;
      __builtin_amdgcn_global_load_lds(
          (const __attribute__((address_space(1))) void*)srcA,
          (__attribute__((address_space(3))) void*)((char*)&Ab[bi][0] + (wid * 64 + i * 512) * 16),
          16, 0, 0);
      const unsigned short* srcB = Wcat + (size_t)(col0 + r) * NM + kt * 64 + cs * 8;
      __builtin_amdgcn_global_load_lds(
          (const __attribute__((address_space(1))) void*)srcB,
          (__attribute__((address_space(3))) void*)((char*)&Bb[bi][0] + (wid * 64 + i * 512) * 16),
          16, 0, 0);
    }
  };

  stage(0, 0);
  stage(1, 1);

  f32x4 acc[8][4] = {};
  for (int kt = 0; kt < 16; ++kt) {
    int bi = kt & 1;
    if (kt < 15) asm volatile("s_waitcnt vmcnt(8)" ::: "memory");
    else         asm volatile("s_waitcnt vmcnt(0)" ::: "memory");
    __builtin_amdgcn_sched_barrier(0);
    __builtin_amdgcn_s_barrier();              // all waves' stages landed

    const char* Ap = (const char*)&Ab[bi][0];
    const char* Bp = (const char*)&Bb[bi][0];
    bf16x8 a0[8], b0[4], a1[8], b1[4];
    #pragma unroll
    for (int m = 0; m < 8; m++) {
      int r = WR * 128 + m * 16 + lr;
      a0[m] = *(const bf16x8*)(Ap + r * 128 + ((lk ^ (r & 7)) * 16));
    }
    #pragma unroll
    for (int n = 0; n < 4; n++) {
      int r = WC * 64 + n * 16 + lr;
      b0[n] = *(const bf16x8*)(Bp + r * 128 + ((lk ^ (r & 7)) * 16));
    }
    #pragma unroll
    for (int m = 0; m < 8; m++)
      #pragma unroll
      for (int n = 0; n < 4; n++)
        acc[m][n] = __builtin_amdgcn_mfma_f32_16x16x32_bf16(a0[m], b0[n], acc[m][n], 0, 0, 0);
    #pragma unroll
    for (int m = 0; m < 8; m++) {
      int r = WR * 128 + m * 16 + lr;
      a1[m] = *(const bf16x8*)(Ap + r * 128 + (((lk + 4) ^ (r & 7)) * 16));
    }
    #pragma unroll
    for (int n = 0; n < 4; n++) {
      int r = WC * 64 + n * 16 + lr;
      b1[n] = *(const bf16x8*)(Bp + r * 128 + (((lk + 4) ^ (r & 7)) * 16));
    }
    asm volatile("s_waitcnt lgkmcnt(0)" ::: "memory");   // all reads of buf bi done
    __builtin_amdgcn_sched_barrier(0);
    __builtin_amdgcn_s_barrier();              // every wave done reading buf bi
    if (kt + 2 < 16) stage(kt + 2, bi);        // overwrite freed buffer
    __builtin_amdgcn_s_setprio(1);
    #pragma unroll
    for (int m = 0; m < 8; m++)
      #pragma unroll
      for (int n = 0; n < 4; n++)
        acc[m][n] = __builtin_amdgcn_mfma_f32_16x16x32_bf16(a1[m], b1[n], acc[m][n], 0, 0, 0);
    __builtin_amdgcn_s_setprio(0);
  }

  // epilogue: zone uniform per block (col0 is 256-aligned within 1024)
  #pragma unroll
  for (int m = 0; m < 8; m++) {
    #pragma unroll
    for (int n = 0; n < 4; n++) {
      int col = col0 + WC * 64 + n * 16 + lr;
      int zone = col >> 10;
      unsigned short* dst = zone == 0 ? q : zone == 1 ? k : zone == 2 ? v : g;
      int cb = col & 1023;
      #pragma unroll
      for (int j = 0; j < 4; j++) {
        int row = row0 + WR * 128 + m * 16 + lk * 4 + j;
        float val = acc[m][n][j];
        if (zone <= 1) val = val / (1.f + expf(-val));        // silu
        else if (zone == 3) val = 1.f / (1.f + expf(-val));   // sigmoid
        dst[(size_t)row * 1024 + cb] = f2bf(val);
      }
    }
  }
}

// ======================================================================
// k_out2: out = u @ Wo^T, 128x128 tile, BK=64 double-buffer, 2-phase.
// ======================================================================
__global__ __launch_bounds__(256) void k_out2(const unsigned short* __restrict__ A,
    const unsigned short* __restrict__ Bt, float* __restrict__ C) {
  __shared__ unsigned short As[2][128 * 64];
  __shared__ unsigned short Bs[2][128 * 64];
  int tid = threadIdx.x;
  int bid = blockIdx.x;                        // 0..255
  int wg = (bid & 7) * 32 + (bid >> 3);        // XCD-bijective swizzle
  int bx = wg & 7, by = wg >> 3;
  int row0 = by * 128, col0 = bx * 128;
  int w = tid >> 6, l = tid & 63;
  int wr = w >> 1, wc = w & 1;
  int lr = l & 15, lk = l >> 4;

  auto stage = [&](int t, int bi) {
    #pragma unroll
    for (int i = 0; i < 4; i++) {
      int idx = tid + i * 256;
      int r = idx >> 3, c = idx & 7;
      int cs = c ^ (r & 7);
      const unsigned short* srcA = A + (size_t)(row0 + r) * NM + t * 64 + cs * 8;
      __builtin_amdgcn_global_load_lds(
          (const __attribute__((address_space(1))) void*)srcA,
          (__attribute__((address_space(3))) void*)((char*)&As[bi][0] + idx * 16),
          16, 0, 0);
      const unsigned short* srcB = Bt + (size_t)(col0 + r) * NM + t * 64 + cs * 8;
      __builtin_amdgcn_global_load_lds(
          (const __attribute__((address_space(1))) void*)srcB,
          (__attribute__((address_space(3))) void*)((char*)&Bs[bi][0] + idx * 16),
          16, 0, 0);
    }
  };

  stage(0, 0);
  asm volatile("s_waitcnt vmcnt(0)" ::: "memory");
  __builtin_amdgcn_s_barrier();

  f32x4 acc[4][4] = {};
  int cur = 0;
  for (int t = 0; t < 16; ++t) {
    if (t < 15) stage(t + 1, cur ^ 1);
    const char* Ap = (const char*)&As[cur][0];
    const char* Bp = (const char*)&Bs[cur][0];
    bf16x8 a[4][2], b[4][2];
    #pragma unroll
    for (int m = 0; m < 4; m++) {
      int ra = wr * 64 + m * 16 + lr;
      #pragma unroll
      for (int kk = 0; kk < 2; kk++)
        a[m][kk] = *(const bf16x8*)(Ap + ra * 128 + (((kk * 4 + lk) ^ (ra & 7)) * 16));
    }
    #pragma unroll
    for (int n = 0; n < 4; n++) {
      int rb = wc * 64 + n * 16 + lr;
      #pragma unroll
      for (int kk = 0; kk < 2; kk++)
        b[n][kk] = *(const bf16x8*)(Bp + rb * 128 + (((kk * 4 + lk) ^ (rb & 7)) * 16));
    }
    __builtin_amdgcn_s_setprio(1);
    #pragma unroll
    for (int kk = 0; kk < 2; kk++)
      #pragma unroll
      for (int m = 0; m < 4; m++)
        #pragma unroll
        for (int n = 0; n < 4; n++)
          acc[m][n] = __builtin_amdgcn_mfma_f32_16x16x32_bf16(a[m][kk], b[n][kk], acc[m][n], 0, 0, 0);
    __builtin_amdgcn_s_setprio(0);
    asm volatile("s_waitcnt vmcnt(0)" ::: "memory");
    __builtin_amdgcn_s_barrier();
    cur ^= 1;
  }
  #pragma unroll
  for (int m = 0; m < 4; m++)
    #pragma unroll
    for (int n = 0; n < 4; n++)
      #pragma unroll
      for (int j = 0; j < 4; j++) {
        int row = row0 + wr * 64 + m * 16 + lk * 4 + j;
        int col = col0 + wc * 64 + n * 16 + lr;
        C[(size_t)row * NM + col] = acc[m][n][j];
      }
}

// ---------------- MFMA attention + fused GroupNorm partial stats (o: bf16) ----------------
__global__ __launch_bounds__(256) void k_attn(const unsigned short* __restrict__ q,
    const unsigned short* __restrict__ kk, const unsigned short* __restrict__ vv,
    const float* __restrict__ cum, unsigned short* __restrict__ o,
    float* __restrict__ psum, float* __restrict__ psq) {
  int it = blockIdx.x, h = blockIdx.y, b = blockIdx.z;
  int i0 = it * 64;
  __shared__ unsigned short Qs[64 * 64];
  __shared__ unsigned short Ks[64 * 64];
  __shared__ unsigned short Ps[64 * 64];
  __shared__ unsigned short Vs[64 * 66];
  __shared__ float ci[64], cj[64];
  __shared__ int jlo_s;
  int tid = threadIdx.x;
  int w = tid >> 6, lane = tid & 63;
  int cl = lane & 15, hi = lane >> 4;
  const size_t hb = (size_t)b * NS * NDI + (size_t)h * ND;
  const float* cumh = cum + (size_t)(b * NH + h) * NS;

  #pragma unroll
  for (int lp = 0; lp < 2; lp++) {
    int idx = tid + lp * 256;
    int r = idx >> 3, cb = (idx & 7) * 16;
    uint4 t = *(const uint4*)(q + hb + (size_t)(i0 + r) * NDI + (cb >> 1));
    *(uint4*)((char*)Qs + r * 128 + (cb ^ ((r & 7) << 4))) = t;
  }
  if (tid < 64) ci[tid] = cumh[i0 + tid];
  // skip-prefix (tighter -25 cutoff: dropped terms < 1.4e-11 * |S| — exact vs threshold)
  if (tid < 64) {
    int jt = tid;
    bool ok = (jt <= it) && (cumh[i0] - cumh[jt * 64 + 63] >= -25.f);
    unsigned long long mask = __ballot(ok);
    if (tid == 0) jlo_s = (int)__builtin_ctzll(mask);
  }
  __syncthreads();
  int jlo = jlo_s;

  int arow = w * 16 + cl;
  int xr = (cl & 7) << 4;
  const char* Qb = (const char*)Qs + arow * 128;
  const char* Pb = (const char*)Ps + arow * 128;
  f32x4 acco[4] = {};

  for (int jt = jlo; jt <= it; jt++) {
    int j0 = jt * 64;
    __syncthreads();
    if (tid < 64) cj[tid] = cumh[j0 + tid];
    __syncthreads();
    #pragma unroll
    for (int lp = 0; lp < 2; lp++) {
      int idx = tid + lp * 256;
      int r = idx >> 3, cb = (idx & 7) * 16;
      uint4 t = *(const uint4*)(kk + hb + (size_t)(j0 + r) * NDI + (cb >> 1));
      *(uint4*)((char*)Ks + r * 128 + (cb ^ ((r & 7) << 4))) = t;
      uint4 tv = *(const uint4*)(vv + hb + (size_t)(j0 + r) * NDI + (cb >> 1));
      unsigned int uv[4]; *(uint4*)uv = tv;
      unsigned int* vd = (unsigned int*)(Vs + r * 66 + (cb >> 1));
      vd[0] = uv[0]; vd[1] = uv[1]; vd[2] = uv[2]; vd[3] = uv[3];
    }
    __syncthreads();
    bf16x8 a0 = *(const bf16x8*)(Qb + ((hi * 16) ^ xr));
    bf16x8 a1 = *(const bf16x8*)(Qb + ((64 + hi * 16) ^ xr));
    f32x4 accs[4] = {};
    #pragma unroll
    for (int jtile = 0; jtile < 4; jtile++) {
      const char* Kb = (const char*)Ks + (jtile * 16 + cl) * 128;
      bf16x8 b0 = *(const bf16x8*)(Kb + ((hi * 16) ^ xr));
      bf16x8 b1 = *(const bf16x8*)(Kb + ((64 + hi * 16) ^ xr));
      accs[jtile] = __builtin_amdgcn_mfma_f32_16x16x32_bf16(a0, b0, accs[jtile], 0, 0, 0);
      accs[jtile] = __builtin_amdgcn_mfma_f32_16x16x32_bf16(a1, b1, accs[jtile], 0, 0, 0);
    }
    #pragma unroll
    for (int jtile = 0; jtile < 4; jtile++) {
      #pragma unroll
      for (int reg = 0; reg < 4; reg++) {
        int irl = w * 16 + hi * 4 + reg;
        int jl = jtile * 16 + cl;
        float dec = ((j0 + jl) <= (i0 + irl)) ? __expf(ci[irl] - cj[jl]) : 0.f;
        float pv = accs[jtile][reg] * dec;
        *(unsigned short*)((char*)Ps + irl * 128 + ((2 * jl) ^ ((irl & 7) << 4))) = f2bf(pv);
      }
    }
    __syncthreads();
    #pragma unroll
    for (int kk2 = 0; kk2 < 2; kk2++) {
      bf16x8 pa = *(const bf16x8*)(Pb + ((kk2 * 64 + hi * 16) ^ xr));
      #pragma unroll
      for (int dt = 0; dt < 4; dt++) {
        bf16x8 vb;
        #pragma unroll
        for (int e = 0; e < 8; e++)
          vb[e] = (short)Vs[(kk2 * 32 + hi * 8 + e) * 66 + dt * 16 + cl];
        acco[dt] = __builtin_amdgcn_mfma_f32_16x16x32_bf16(pa, vb, acco[dt], 0, 0, 0);
      }
    }
  }
  #pragma unroll
  for (int dt = 0; dt < 4; dt++) {
    #pragma unroll
    for (int reg = 0; reg < 4; reg++) {
      int row = i0 + w * 16 + hi * 4 + reg;
      o[hb + (size_t)row * NDI + dt * 16 + cl] = f2bf(acco[dt][reg]);
    }
  }
  __syncthreads();
  float* ls = (float*)Ps;
  float* lq = ls + 256;
  float sm = 0.f, sq = 0.f;
  #pragma unroll
  for (int dt = 0; dt < 4; dt++)
    #pragma unroll
    for (int reg = 0; reg < 4; reg++) { float t2 = acco[dt][reg]; sm += t2; sq += t2 * t2; }
  ls[tid] = sm; lq[tid] = sq;
  __syncthreads();
  for (int off = 128; off > 0; off >>= 1) {
    if (tid < off) { ls[tid] += ls[tid + off]; lq[tid] += lq[tid + off]; }
    __syncthreads();
  }
  if (tid == 0) {
    atomicAdd(&psum[b * NH + h], ls[0]);
    atomicAdd(&psq[b * NH + h], lq[0]);
  }
}

// ---------------- u = (groupnorm(o)*w+b)*gate, bf16 out (stats inline) ----------------
__global__ __launch_bounds__(256) void k_gate(const unsigned short* __restrict__ o,
    const unsigned short* __restrict__ gsig, const float* __restrict__ psum,
    const float* __restrict__ psq, const float* __restrict__ gnw,
    const float* __restrict__ gnb, unsigned short* __restrict__ u) {
  int idx4 = blockIdx.x * 256 + threadIdx.x;
  size_t base = (size_t)idx4 * 4;
  int c = (int)(base & (NDI - 1));
  int row = (int)(base >> 10);
  int b = row >> 11;
  int h = c >> 6;
  int g = b * NH + h;
  float n = (float)(NS * ND);
  float mean = psum[g] / n;
  float var = psq[g] / n - mean * mean;
  float rstd = rsqrtf(var + 1e-5f);
  ushort4 ov = *(const ushort4*)(o + base);
  ushort4 gv = *(const ushort4*)(gsig + base);
  float4 w4 = *(const float4*)(gnw + c);
  float4 b4 = *(const float4*)(gnb + c);
  unsigned short r[4];
  r[0] = f2bf(((bf2f(ov.x) - mean) * rstd * w4.x + b4.x) * bf2f(gv.x));
  r[1] = f2bf(((bf2f(ov.y) - mean) * rstd * w4.y + b4.y) * bf2f(gv.y));
  r[2] = f2bf(((bf2f(ov.z) - mean) * rstd * w4.z + b4.z) * bf2f(gv.z));
  r[3] = f2bf(((bf2f(ov.w) - mean) * rstd * w4.w + b4.w) * bf2f(gv.w));
  *(ushort4*)(u + base) = *(const ushort4*)r;
}

extern "C" void kernel_launch(void* const* d_in, const int* in_sizes, int n_in,
                              void* d_out, int out_size, void* d_ws, size_t ws_size,
                              hipStream_t stream) {
  const float* x   = (const float*)d_in[0];
  const float* Wq  = (const float*)d_in[1];
  const float* Wk  = (const float*)d_in[2];
  const float* Wv  = (const float*)d_in[3];
  const float* Wg  = (const float*)d_in[4];
  const float* Wa  = (const float*)d_in[5];
  const float* ba  = (const float*)d_in[6];
  const float* Wo  = (const float*)d_in[7];
  const float* gnw = (const float*)d_in[8];
  const float* gnb = (const float*)d_in[9];
  float* out = (float*)d_out;

  const size_t NTOK = (size_t)NB * NS;        // 4096
  char* p = (char*)d_ws;
  float* la4 = (float*)p;                 p += (size_t)4 * 32 * NS * 4;   // 1 MB
  float* cum = (float*)p;                 p += (size_t)NB * NH * NS * 4;
  float* psum = (float*)p;                p += 32 * 4;
  float* psq  = (float*)p;                p += 32 * 4;
  p = (char*)(((uintptr_t)p + 255) & ~(uintptr_t)255);
  unsigned short* xb   = (unsigned short*)p; p += NTOK * NM * 2;        // 8 MB
  unsigned short* Wcat = (unsigned short*)p; p += (size_t)4 * NM * NDI * 2; // 8 MB
  unsigned short* wto  = (unsigned short*)p; p += (size_t)NDI * NM * 2;
  unsigned short* wa_pad = (unsigned short*)p; p += (size_t)128 * NM * 2;
  unsigned short* q  = (unsigned short*)p;  p += NTOK * NDI * 2;
  unsigned short* k  = (unsigned short*)p;  p += NTOK * NDI * 2;
  unsigned short* v  = (unsigned short*)p;  p += NTOK * NDI * 2;
  unsigned short* g  = (unsigned short*)p;  p += NTOK * NDI * 2;
  unsigned short* u  = (unsigned short*)p;  p += NTOK * NDI * 2;
  unsigned short* o  = (unsigned short*)p;  p += NTOK * NDI * 2;

  unsigned short* wtq = Wcat;
  unsigned short* wtk = Wcat + (size_t)NM * NDI;
  unsigned short* wtv = Wcat + (size_t)2 * NM * NDI;
  unsigned short* wtg = Wcat + (size_t)3 * NM * NDI;

  k_prep    <<<dim3(7680), 256, 0, stream>>>(x, Wq, Wk, Wv, Wg, Wo, Wa,
                                             xb, wtq, wtk, wtv, wtg, wto, wa_pad);
  k_la_gemm <<<dim3(4, 32), 256, 0, stream>>>(xb, wa_pad, la4);
  k_cumsum  <<<dim3(NB * NH), 256, 0, stream>>>(la4, ba, cum, psum, psq);
  k_proj8   <<<dim3(256), 512, 0, stream>>>(xb, Wcat, q, k, v, g);
  k_attn    <<<dim3(32, NH, NB), 256, 0, stream>>>(q, k, v, cum, o, psum, psq);
  k_gate    <<<dim3(4096), 256, 0, stream>>>(o, g, psum, psq, gnw, gnb, u);
  k_out2    <<<dim3(256), 256, 0, stream>>>(u, wto, out);
}

// Round 12
// 121.635 us; speedup vs baseline: 1.2503x; 1.0159x over previous
//
#include <hip/hip_runtime.h>
#include <math.h>
#include <stdint.h>

typedef __attribute__((ext_vector_type(4))) float f32x4;
typedef __attribute__((ext_vector_type(8))) short bf16x8;

constexpr int NB = 2;       // B
constexpr int NS = 2048;    // S
constexpr int NM = 1024;    // D_MODEL
constexpr int NH = 16;      // H
constexpr int ND = 64;      // D
constexpr int NDI = 1024;   // H*D

__device__ __forceinline__ float bf2f(unsigned short u) {
  uint32_t x = ((uint32_t)u) << 16; float f; __builtin_memcpy(&f, &x, 4); return f;
}
__device__ __forceinline__ unsigned short f2bf(float f) {
  uint32_t x; __builtin_memcpy(&x, &f, 4);
  x += 0x7FFFu + ((x >> 16) & 1u);            // RNE (finite values)
  return (unsigned short)(x >> 16);
}

// ---------------- fused preprocessing: cast x, transpose-cast 5 W, pad Wa ----------------
__global__ __launch_bounds__(256) void k_prep(const float* __restrict__ x,
    const float* __restrict__ w0, const float* __restrict__ w1,
    const float* __restrict__ w2, const float* __restrict__ w3,
    const float* __restrict__ w4, const float* __restrict__ Wa,
    unsigned short* __restrict__ xb,
    unsigned short* __restrict__ t0, unsigned short* __restrict__ t1,
    unsigned short* __restrict__ t2, unsigned short* __restrict__ t3,
    unsigned short* __restrict__ t4, unsigned short* __restrict__ wa_pad) {
  int bid = blockIdx.x;
  if (bid < 2048) {                            // ---- cast x ----
    int i = bid * 256 + threadIdx.x;
    const float4* p = (const float4*)(x + (size_t)i * 8);
    float4 a = p[0], b = p[1];
    unsigned short r[8] = {f2bf(a.x), f2bf(a.y), f2bf(a.z), f2bf(a.w),
                           f2bf(b.x), f2bf(b.y), f2bf(b.z), f2bf(b.w)};
    *(uint4*)(xb + (size_t)i * 8) = *(const uint4*)r;
  } else if (bid < 7168) {                     // ---- castT5 ----
    __shared__ float tile[32][33];
    int w = bid - 2048;
    int z = w >> 10, within = w & 1023;
    const float* src = z == 0 ? w0 : z == 1 ? w1 : z == 2 ? w2 : z == 3 ? w3 : w4;
    unsigned short* dst = z == 0 ? t0 : z == 1 ? t1 : z == 2 ? t2 : z == 3 ? t3 : t4;
    int c0 = (within & 31) * 32, r0 = (within >> 5) * 32;
    int tx = threadIdx.x & 31, ty = threadIdx.x >> 5;
    #pragma unroll
    for (int i = 0; i < 4; i++)
      tile[ty + i * 8][tx] = src[(size_t)(r0 + ty + i * 8) * 1024 + c0 + tx];
    __syncthreads();
    #pragma unroll
    for (int i = 0; i < 4; i++)
      dst[(size_t)(c0 + ty + i * 8) * 1024 + r0 + tx] = f2bf(tile[tx][ty + i * 8]);
  } else {                                     // ---- wa_pad ----
    int idx = (bid - 7168) * 256 + threadIdx.x;
    int h = idx >> 10, k2 = idx & 1023;
    wa_pad[idx] = (h < 16) ? f2bf(Wa[k2 * 16 + h]) : (unsigned short)0;
  }
}

// ---------------- la partial GEMM: K-split by 8 ----------------
__global__ __launch_bounds__(256) void k_la_gemm(const unsigned short* __restrict__ xb,
    const unsigned short* __restrict__ wa_pad, float* __restrict__ la8) {
  __shared__ unsigned short As[128 * 32];
  __shared__ unsigned short Bs[128 * 32];
  int tid = threadIdx.x;
  int row0 = blockIdx.y * 128;
  int kbeg = blockIdx.x * 128;
  float* Cp = la8 + (size_t)blockIdx.x * (32 * 2048);
  int w = tid >> 6, l = tid & 63;
  int wr = w >> 1, wc = w & 1;
  int lr = l & 15, lk = l >> 4;
  f32x4 acc[4] = {};
  for (int k0 = kbeg; k0 < kbeg + 128; k0 += 32) {
    __syncthreads();
    #pragma unroll
    for (int i = 0; i < 2; i++) {
      int idx = tid + i * 256;
      int r = idx >> 2, c = idx & 3;
      int cs = c ^ ((r >> 1) & 3);
      const unsigned short* srcA = xb + (size_t)(row0 + r) * NM + k0 + cs * 8;
      const unsigned short* srcB = wa_pad + (size_t)r * NM + k0 + cs * 8;
      __builtin_amdgcn_global_load_lds(
          (const __attribute__((address_space(1))) void*)srcA,
          (__attribute__((address_space(3))) void*)((char*)As + (w * 64 + i * 256) * 16),
          16, 0, 0);
      __builtin_amdgcn_global_load_lds(
          (const __attribute__((address_space(1))) void*)srcB,
          (__attribute__((address_space(3))) void*)((char*)Bs + (w * 64 + i * 256) * 16),
          16, 0, 0);
    }
    __syncthreads();
    if (wc == 0) {
      bf16x8 b = *(const bf16x8*)&Bs[lr * 32 + (lk ^ ((lr >> 1) & 3)) * 8];
      #pragma unroll
      for (int m = 0; m < 4; m++) {
        int ra = wr * 64 + m * 16 + lr;
        bf16x8 a = *(const bf16x8*)&As[ra * 32 + (lk ^ ((ra >> 1) & 3)) * 8];
        acc[m] = __builtin_amdgcn_mfma_f32_16x16x32_bf16(a, b, acc[m], 0, 0, 0);
      }
    }
  }
  if (wc == 0) {
    #pragma unroll
    for (int m = 0; m < 4; m++) {
      #pragma unroll
      for (int j = 0; j < 4; j++) {
        int row = row0 + wr * 64 + m * 16 + lk * 4 + j;
        int bb = row >> 11, s = row & 2047;
        Cp[((size_t)(bb * 16 + lr)) * 2048 + s] = acc[m][j];
      }
    }
  }
}

// ---------------- cumsum: sum 8 K-slices + bias, -softplus, scan; zero psum/psq ----------------
__global__ __launch_bounds__(256) void k_cumsum(const float* __restrict__ la8,
    const float* __restrict__ ba, float* __restrict__ cum,
    float* __restrict__ psum, float* __restrict__ psq) {
  int g = blockIdx.x;
  int h = g & 15;
  if (threadIdx.x == 0) { psum[g] = 0.f; psq[g] = 0.f; }
  float bah = ba[h];
  const float* p0 = la8 + (size_t)g * NS;
  float* out = cum + (size_t)g * NS;
  __shared__ float part[256];
  float v[8]; float sum = 0.f;
  int base = threadIdx.x * 8;
  #pragma unroll
  for (int i = 0; i < 8; i++) {
    int s = base + i;
    float z = bah;
    #pragma unroll
    for (int sl = 0; sl < 8; sl++) z += p0[sl * 65536 + s];
    float sp = fmaxf(z, 0.f) + log1pf(expf(-fabsf(z)));
    v[i] = -sp; sum += v[i];
  }
  part[threadIdx.x] = sum;
  __syncthreads();
  for (int off = 1; off < 256; off <<= 1) {
    float add = (threadIdx.x >= off) ? part[threadIdx.x - off] : 0.f;
    __syncthreads();
    part[threadIdx.x] += add;
    __syncthreads();
  }
  float run = (threadIdx.x > 0) ? part[threadIdx.x - 1] : 0.f;
  #pragma unroll
  for (int i = 0; i < 8; i++) { run += v[i]; out[base + i] = run; }
}

// ======================================================================
// k_proj8 (r4-proven, accepted): fused q|k|v|g, 256x256 tile, BK=64,
// counted-vmcnt double buffer, source-swizzled LDS, setprio.
// ======================================================================
__global__ __launch_bounds__(512, 2) void k_proj8(
    const unsigned short* __restrict__ A,
    const unsigned short* __restrict__ Wcat,
    unsigned short* __restrict__ q, unsigned short* __restrict__ k,
    unsigned short* __restrict__ v, unsigned short* __restrict__ g) {
  __shared__ unsigned short Ab[2][256 * 64];   // 64 KB
  __shared__ unsigned short Bb[2][256 * 64];   // 64 KB
  int tid = threadIdx.x;
  int bid = blockIdx.x;                        // 0..255
  int wg = (bid & 7) * 32 + (bid >> 3);        // XCD-bijective swizzle
  int bx = wg & 15, by = wg >> 4;
  int row0 = by * 256, col0 = bx * 256;
  int wid = tid >> 6, lane = tid & 63;
  int WR = wid >> 2, WC = wid & 3;             // 2M x 4N wave grid
  int lr = lane & 15, lk = lane >> 4;

  auto stage = [&](int kt, int bi) {
    #pragma unroll
    for (int i = 0; i < 4; i++) {
      int idx = tid + i * 512;                 // chunk 0..2047
      int r = idx >> 3, c = idx & 7;
      int cs = c ^ (r & 7);                    // pre-swizzled source (T2, rule 21)
      const unsigned short* srcA = A + (size_t)(row0 + r) * NM + kt * 64 + cs * 8;
      __builtin_amdgcn_global_load_lds(
          (const __attribute__((address_space(1))) void*)srcA,
          (__attribute__((address_space(3))) void*)((char*)&Ab[bi][0] + (wid * 64 + i * 512) * 16),
          16, 0, 0);
      const unsigned short* srcB = Wcat + (size_t)(col0 + r) * NM + kt * 64 + cs * 8;
      __builtin_amdgcn_global_load_lds(
          (const __attribute__((address_space(1))) void*)srcB,
          (__attribute__((address_space(3))) void*)((char*)&Bb[bi][0] + (wid * 64 + i * 512) * 16),
          16, 0, 0);
    }
  };

  stage(0, 0);
  stage(1, 1);

  f32x4 acc[8][4] = {};
  for (int kt = 0; kt < 16; ++kt) {
    int bi = kt & 1;
    if (kt < 15) asm volatile("s_waitcnt vmcnt(8)" ::: "memory");
    else         asm volatile("s_waitcnt vmcnt(0)" ::: "memory");
    __builtin_amdgcn_sched_barrier(0);
    __builtin_amdgcn_s_barrier();              // all waves' stages landed

    const char* Ap = (const char*)&Ab[bi][0];
    const char* Bp = (const char*)&Bb[bi][0];
    bf16x8 a0[8], b0[4], a1[8], b1[4];
    #pragma unroll
    for (int m = 0; m < 8; m++) {
      int r = WR * 128 + m * 16 + lr;
      a0[m] = *(const bf16x8*)(Ap + r * 128 + ((lk ^ (r & 7)) * 16));
    }
    #pragma unroll
    for (int n = 0; n < 4; n++) {
      int r = WC * 64 + n * 16 + lr;
      b0[n] = *(const bf16x8*)(Bp + r * 128 + ((lk ^ (r & 7)) * 16));
    }
    #pragma unroll
    for (int m = 0; m < 8; m++)
      #pragma unroll
      for (int n = 0; n < 4; n++)
        acc[m][n] = __builtin_amdgcn_mfma_f32_16x16x32_bf16(a0[m], b0[n], acc[m][n], 0, 0, 0);
    #pragma unroll
    for (int m = 0; m < 8; m++) {
      int r = WR * 128 + m * 16 + lr;
      a1[m] = *(const bf16x8*)(Ap + r * 128 + (((lk + 4) ^ (r & 7)) * 16));
    }
    #pragma unroll
    for (int n = 0; n < 4; n++) {
      int r = WC * 64 + n * 16 + lr;
      b1[n] = *(const bf16x8*)(Bp + r * 128 + (((lk + 4) ^ (r & 7)) * 16));
    }
    asm volatile("s_waitcnt lgkmcnt(0)" ::: "memory");   // all reads of buf bi done
    __builtin_amdgcn_sched_barrier(0);
    __builtin_amdgcn_s_barrier();              // every wave done reading buf bi
    if (kt + 2 < 16) stage(kt + 2, bi);        // overwrite freed buffer
    __builtin_amdgcn_s_setprio(1);
    #pragma unroll
    for (int m = 0; m < 8; m++)
      #pragma unroll
      for (int n = 0; n < 4; n++)
        acc[m][n] = __builtin_amdgcn_mfma_f32_16x16x32_bf16(a1[m], b1[n], acc[m][n], 0, 0, 0);
    __builtin_amdgcn_s_setprio(0);
  }

  // epilogue: zone uniform per block (col0 is 256-aligned within 1024)
  #pragma unroll
  for (int m = 0; m < 8; m++) {
    #pragma unroll
    for (int n = 0; n < 4; n++) {
      int col = col0 + WC * 64 + n * 16 + lr;
      int zone = col >> 10;
      unsigned short* dst = zone == 0 ? q : zone == 1 ? k : zone == 2 ? v : g;
      int cb = col & 1023;
      #pragma unroll
      for (int j = 0; j < 4; j++) {
        int row = row0 + WR * 128 + m * 16 + lk * 4 + j;
        float val = acc[m][n][j];
        if (zone <= 1) val = val / (1.f + expf(-val));        // silu
        else if (zone == 3) val = 1.f / (1.f + expf(-val));   // sigmoid
        dst[(size_t)row * 1024 + cb] = f2bf(val);
      }
    }
  }
}

// ======================================================================
// k_out2: out = u @ Wo^T, 128x128 tile, BK=64 double-buffer, 2-phase.
// ======================================================================
__global__ __launch_bounds__(256) void k_out2(const unsigned short* __restrict__ A,
    const unsigned short* __restrict__ Bt, float* __restrict__ C) {
  __shared__ unsigned short As[2][128 * 64];
  __shared__ unsigned short Bs[2][128 * 64];
  int tid = threadIdx.x;
  int bid = blockIdx.x;                        // 0..255
  int wg = (bid & 7) * 32 + (bid >> 3);        // XCD-bijective swizzle
  int bx = wg & 7, by = wg >> 3;
  int row0 = by * 128, col0 = bx * 128;
  int w = tid >> 6, l = tid & 63;
  int wr = w >> 1, wc = w & 1;
  int lr = l & 15, lk = l >> 4;

  auto stage = [&](int t, int bi) {
    #pragma unroll
    for (int i = 0; i < 4; i++) {
      int idx = tid + i * 256;
      int r = idx >> 3, c = idx & 7;
      int cs = c ^ (r & 7);
      const unsigned short* srcA = A + (size_t)(row0 + r) * NM + t * 64 + cs * 8;
      __builtin_amdgcn_global_load_lds(
          (const __attribute__((address_space(1))) void*)srcA,
          (__attribute__((address_space(3))) void*)((char*)&As[bi][0] + idx * 16),
          16, 0, 0);
      const unsigned short* srcB = Bt + (size_t)(col0 + r) * NM + t * 64 + cs * 8;
      __builtin_amdgcn_global_load_lds(
          (const __attribute__((address_space(1))) void*)srcB,
          (__attribute__((address_space(3))) void*)((char*)&Bs[bi][0] + idx * 16),
          16, 0, 0);
    }
  };

  stage(0, 0);
  asm volatile("s_waitcnt vmcnt(0)" ::: "memory");
  __builtin_amdgcn_s_barrier();

  f32x4 acc[4][4] = {};
  int cur = 0;
  for (int t = 0; t < 16; ++t) {
    if (t < 15) stage(t + 1, cur ^ 1);
    const char* Ap = (const char*)&As[cur][0];
    const char* Bp = (const char*)&Bs[cur][0];
    bf16x8 a[4][2], b[4][2];
    #pragma unroll
    for (int m = 0; m < 4; m++) {
      int ra = wr * 64 + m * 16 + lr;
      #pragma unroll
      for (int kk = 0; kk < 2; kk++)
        a[m][kk] = *(const bf16x8*)(Ap + ra * 128 + (((kk * 4 + lk) ^ (ra & 7)) * 16));
    }
    #pragma unroll
    for (int n = 0; n < 4; n++) {
      int rb = wc * 64 + n * 16 + lr;
      #pragma unroll
      for (int kk = 0; kk < 2; kk++)
        b[n][kk] = *(const bf16x8*)(Bp + rb * 128 + (((kk * 4 + lk) ^ (rb & 7)) * 16));
    }
    __builtin_amdgcn_s_setprio(1);
    #pragma unroll
    for (int kk = 0; kk < 2; kk++)
      #pragma unroll
      for (int m = 0; m < 4; m++)
        #pragma unroll
        for (int n = 0; n < 4; n++)
          acc[m][n] = __builtin_amdgcn_mfma_f32_16x16x32_bf16(a[m][kk], b[n][kk], acc[m][n], 0, 0, 0);
    __builtin_amdgcn_s_setprio(0);
    asm volatile("s_waitcnt vmcnt(0)" ::: "memory");
    __builtin_amdgcn_s_barrier();
    cur ^= 1;
  }
  #pragma unroll
  for (int m = 0; m < 4; m++)
    #pragma unroll
    for (int n = 0; n < 4; n++)
      #pragma unroll
      for (int j = 0; j < 4; j++) {
        int row = row0 + wr * 64 + m * 16 + lk * 4 + j;
        int col = col0 + wc * 64 + n * 16 + lr;
        C[(size_t)row * NM + col] = acc[m][n][j];
      }
}

// ---------------- MFMA attention + fused GroupNorm partial stats (o: bf16) ----------------
// V stored TRANSPOSED in LDS (Vt[d][j], stride 66 hw): PV B-fragment becomes
// 4x ds_read_b32 (j-contiguous) instead of 8 scalar u16 reads.
__global__ __launch_bounds__(256) void k_attn(const unsigned short* __restrict__ q,
    const unsigned short* __restrict__ kk, const unsigned short* __restrict__ vv,
    const float* __restrict__ cum, unsigned short* __restrict__ o,
    float* __restrict__ psum, float* __restrict__ psq) {
  int it = blockIdx.x, h = blockIdx.y, b = blockIdx.z;
  int i0 = it * 64;
  __shared__ unsigned short Qs[64 * 64];
  __shared__ unsigned short Ks[64 * 64];
  __shared__ unsigned short Ps[64 * 64];
  __shared__ unsigned short Vt[64 * 66];       // [d][j], stride 66 halfwords
  __shared__ float ci[64], cj[64];
  __shared__ int jlo_s;
  int tid = threadIdx.x;
  int w = tid >> 6, lane = tid & 63;
  int cl = lane & 15, hi = lane >> 4;
  const size_t hb = (size_t)b * NS * NDI + (size_t)h * ND;
  const float* cumh = cum + (size_t)(b * NH + h) * NS;

  #pragma unroll
  for (int lp = 0; lp < 2; lp++) {
    int idx = tid + lp * 256;
    int r = idx >> 3, cb = (idx & 7) * 16;
    uint4 t = *(const uint4*)(q + hb + (size_t)(i0 + r) * NDI + (cb >> 1));
    *(uint4*)((char*)Qs + r * 128 + (cb ^ ((r & 7) << 4))) = t;
  }
  if (tid < 64) ci[tid] = cumh[i0 + tid];
  // skip-prefix (tight -25 cutoff: dropped terms < 1.4e-11)
  if (tid < 64) {
    int jt = tid;
    bool ok = (jt <= it) && (cumh[i0] - cumh[jt * 64 + 63] >= -25.f);
    unsigned long long mask = __ballot(ok);
    if (tid == 0) jlo_s = (int)__builtin_ctzll(mask);
  }
  __syncthreads();
  int jlo = jlo_s;

  int arow = w * 16 + cl;
  int xr = (cl & 7) << 4;
  const char* Qb = (const char*)Qs + arow * 128;
  const char* Pb = (const char*)Ps + arow * 128;
  f32x4 acco[4] = {};

  for (int jt = jlo; jt <= it; jt++) {
    int j0 = jt * 64;
    __syncthreads();
    if (tid < 64) cj[tid] = cumh[j0 + tid];
    __syncthreads();
    #pragma unroll
    for (int lp = 0; lp < 2; lp++) {
      int idx = tid + lp * 256;
      int r = idx >> 3, cb = (idx & 7) * 16;
      uint4 t = *(const uint4*)(kk + hb + (size_t)(j0 + r) * NDI + (cb >> 1));
      *(uint4*)((char*)Ks + r * 128 + (cb ^ ((r & 7) << 4))) = t;
      uint4 tv = *(const uint4*)(vv + hb + (size_t)(j0 + r) * NDI + (cb >> 1));
      unsigned short us[8]; *(uint4*)us = tv;
      int c8 = (idx & 7) * 8;                  // V column base (d)
      #pragma unroll
      for (int e = 0; e < 8; e++) Vt[(c8 + e) * 66 + r] = us[e];   // transpose write
    }
    __syncthreads();
    bf16x8 a0 = *(const bf16x8*)(Qb + ((hi * 16) ^ xr));
    bf16x8 a1 = *(const bf16x8*)(Qb + ((64 + hi * 16) ^ xr));
    f32x4 accs[4] = {};
    #pragma unroll
    for (int jtile = 0; jtile < 4; jtile++) {
      const char* Kb = (const char*)Ks + (jtile * 16 + cl) * 128;
      bf16x8 b0 = *(const bf16x8*)(Kb + ((hi * 16) ^ xr));
      bf16x8 b1 = *(const bf16x8*)(Kb + ((64 + hi * 16) ^ xr));
      accs[jtile] = __builtin_amdgcn_mfma_f32_16x16x32_bf16(a0, b0, accs[jtile], 0, 0, 0);
      accs[jtile] = __builtin_amdgcn_mfma_f32_16x16x32_bf16(a1, b1, accs[jtile], 0, 0, 0);
    }
    #pragma unroll
    for (int jtile = 0; jtile < 4; jtile++) {
      #pragma unroll
      for (int reg = 0; reg < 4; reg++) {
        int irl = w * 16 + hi * 4 + reg;
        int jl = jtile * 16 + cl;
        float dec = ((j0 + jl) <= (i0 + irl)) ? __expf(ci[irl] - cj[jl]) : 0.f;
        float pv = accs[jtile][reg] * dec;
        *(unsigned short*)((char*)Ps + irl * 128 + ((2 * jl) ^ ((irl & 7) << 4))) = f2bf(pv);
      }
    }
    __syncthreads();
    #pragma unroll
    for (int kk2 = 0; kk2 < 2; kk2++) {
      bf16x8 pa = *(const bf16x8*)(Pb + ((kk2 * 64 + hi * 16) ^ xr));
      #pragma unroll
      for (int dt = 0; dt < 4; dt++) {
        const unsigned int* vp = (const unsigned int*)(Vt + (dt * 16 + cl) * 66 + kk2 * 32 + hi * 8);
        uint4 tmp;                             // 4x ds_read_b32 (4B-aligned always)
        tmp.x = vp[0]; tmp.y = vp[1]; tmp.z = vp[2]; tmp.w = vp[3];
        bf16x8 vb = *(const bf16x8*)&tmp;
        acco[dt] = __builtin_amdgcn_mfma_f32_16x16x32_bf16(pa, vb, acco[dt], 0, 0, 0);
      }
    }
  }
  #pragma unroll
  for (int dt = 0; dt < 4; dt++) {
    #pragma unroll
    for (int reg = 0; reg < 4; reg++) {
      int row = i0 + w * 16 + hi * 4 + reg;
      o[hb + (size_t)row * NDI + dt * 16 + cl] = f2bf(acco[dt][reg]);
    }
  }
  __syncthreads();
  float* ls = (float*)Ps;
  float* lq = ls + 256;
  float sm = 0.f, sq = 0.f;
  #pragma unroll
  for (int dt = 0; dt < 4; dt++)
    #pragma unroll
    for (int reg = 0; reg < 4; reg++) { float t2 = acco[dt][reg]; sm += t2; sq += t2 * t2; }
  ls[tid] = sm; lq[tid] = sq;
  __syncthreads();
  for (int off = 128; off > 0; off >>= 1) {
    if (tid < off) { ls[tid] += ls[tid + off]; lq[tid] += lq[tid + off]; }
    __syncthreads();
  }
  if (tid == 0) {
    atomicAdd(&psum[b * NH + h], ls[0]);
    atomicAdd(&psq[b * NH + h], lq[0]);
  }
}

// ---------------- u = (groupnorm(o)*w+b)*gate, bf16 out (stats inline) ----------------
__global__ __launch_bounds__(256) void k_gate(const unsigned short* __restrict__ o,
    const unsigned short* __restrict__ gsig, const float* __restrict__ psum,
    const float* __restrict__ psq, const float* __restrict__ gnw,
    const float* __restrict__ gnb, unsigned short* __restrict__ u) {
  int idx4 = blockIdx.x * 256 + threadIdx.x;
  size_t base = (size_t)idx4 * 4;
  int c = (int)(base & (NDI - 1));
  int row = (int)(base >> 10);
  int b = row >> 11;
  int h = c >> 6;
  int g = b * NH + h;
  float n = (float)(NS * ND);
  float mean = psum[g] / n;
  float var = psq[g] / n - mean * mean;
  float rstd = rsqrtf(var + 1e-5f);
  ushort4 ov = *(const ushort4*)(o + base);
  ushort4 gv = *(const ushort4*)(gsig + base);
  float4 w4 = *(const float4*)(gnw + c);
  float4 b4 = *(const float4*)(gnb + c);
  unsigned short r[4];
  r[0] = f2bf(((bf2f(ov.x) - mean) * rstd * w4.x + b4.x) * bf2f(gv.x));
  r[1] = f2bf(((bf2f(ov.y) - mean) * rstd * w4.y + b4.y) * bf2f(gv.y));
  r[2] = f2bf(((bf2f(ov.z) - mean) * rstd * w4.z + b4.z) * bf2f(gv.z));
  r[3] = f2bf(((bf2f(ov.w) - mean) * rstd * w4.w + b4.w) * bf2f(gv.w));
  *(ushort4*)(u + base) = *(const ushort4*)r;
}

extern "C" void kernel_launch(void* const* d_in, const int* in_sizes, int n_in,
                              void* d_out, int out_size, void* d_ws, size_t ws_size,
                              hipStream_t stream) {
  const float* x   = (const float*)d_in[0];
  const float* Wq  = (const float*)d_in[1];
  const float* Wk  = (const float*)d_in[2];
  const float* Wv  = (const float*)d_in[3];
  const float* Wg  = (const float*)d_in[4];
  const float* Wa  = (const float*)d_in[5];
  const float* ba  = (const float*)d_in[6];
  const float* Wo  = (const float*)d_in[7];
  const float* gnw = (const float*)d_in[8];
  const float* gnb = (const float*)d_in[9];
  float* out = (float*)d_out;

  const size_t NTOK = (size_t)NB * NS;        // 4096
  char* p = (char*)d_ws;
  float* la8 = (float*)p;                 p += (size_t)8 * 32 * NS * 4;   // 2 MB
  float* cum = (float*)p;                 p += (size_t)NB * NH * NS * 4;
  float* psum = (float*)p;                p += 32 * 4;
  float* psq  = (float*)p;                p += 32 * 4;
  p = (char*)(((uintptr_t)p + 255) & ~(uintptr_t)255);
  unsigned short* xb   = (unsigned short*)p; p += NTOK * NM * 2;        // 8 MB
  unsigned short* Wcat = (unsigned short*)p; p += (size_t)4 * NM * NDI * 2; // 8 MB
  unsigned short* wto  = (unsigned short*)p; p += (size_t)NDI * NM * 2;
  unsigned short* wa_pad = (unsigned short*)p; p += (size_t)128 * NM * 2;
  unsigned short* q  = (unsigned short*)p;  p += NTOK * NDI * 2;
  unsigned short* k  = (unsigned short*)p;  p += NTOK * NDI * 2;
  unsigned short* v  = (unsigned short*)p;  p += NTOK * NDI * 2;
  unsigned short* g  = (unsigned short*)p;  p += NTOK * NDI * 2;
  unsigned short* u  = (unsigned short*)p;  p += NTOK * NDI * 2;
  unsigned short* o  = (unsigned short*)p;  p += NTOK * NDI * 2;

  unsigned short* wtq = Wcat;
  unsigned short* wtk = Wcat + (size_t)NM * NDI;
  unsigned short* wtv = Wcat + (size_t)2 * NM * NDI;
  unsigned short* wtg = Wcat + (size_t)3 * NM * NDI;

  k_prep    <<<dim3(7680), 256, 0, stream>>>(x, Wq, Wk, Wv, Wg, Wo, Wa,
                                             xb, wtq, wtk, wtv, wtg, wto, wa_pad);
  k_la_gemm <<<dim3(8, 32), 256, 0, stream>>>(xb, wa_pad, la8);
  k_cumsum  <<<dim3(NB * NH), 256, 0, stream>>>(la8, ba, cum, psum, psq);
  k_proj8   <<<dim3(256), 512, 0, stream>>>(xb, Wcat, q, k, v, g);
  k_attn    <<<dim3(32, NH, NB), 256, 0, stream>>>(q, k, v, cum, o, psum, psq);
  k_gate    <<<dim3(4096), 256, 0, stream>>>(o, g, psum, psq, gnw, gnb, u);
  k_out2    <<<dim3(256), 256, 0, stream>>>(u, wto, out);
}

// Round 13
// 118.595 us; speedup vs baseline: 1.2823x; 1.0256x over previous
//
#include <hip/hip_runtime.h>
#include <math.h>
#include <stdint.h>

typedef __attribute__((ext_vector_type(4))) float f32x4;
typedef __attribute__((ext_vector_type(8))) short bf16x8;

constexpr int NB = 2;       // B
constexpr int NS = 2048;    // S
constexpr int NM = 1024;    // D_MODEL
constexpr int NH = 16;      // H
constexpr int ND = 64;      // D
constexpr int NDI = 1024;   // H*D

__device__ __forceinline__ float bf2f(unsigned short u) {
  uint32_t x = ((uint32_t)u) << 16; float f; __builtin_memcpy(&f, &x, 4); return f;
}
__device__ __forceinline__ unsigned short f2bf(float f) {
  uint32_t x; __builtin_memcpy(&x, &f, 4);
  x += 0x7FFFu + ((x >> 16) & 1u);            // RNE (finite values)
  return (unsigned short)(x >> 16);
}

// ---------------- fused preprocessing: cast x, transpose-cast 5 W, pad Wa ----------------
__global__ __launch_bounds__(256) void k_prep(const float* __restrict__ x,
    const float* __restrict__ w0, const float* __restrict__ w1,
    const float* __restrict__ w2, const float* __restrict__ w3,
    const float* __restrict__ w4, const float* __restrict__ Wa,
    unsigned short* __restrict__ xb,
    unsigned short* __restrict__ t0, unsigned short* __restrict__ t1,
    unsigned short* __restrict__ t2, unsigned short* __restrict__ t3,
    unsigned short* __restrict__ t4, unsigned short* __restrict__ wa_pad) {
  int bid = blockIdx.x;
  if (bid < 2048) {                            // ---- cast x ----
    int i = bid * 256 + threadIdx.x;
    const float4* p = (const float4*)(x + (size_t)i * 8);
    float4 a = p[0], b = p[1];
    unsigned short r[8] = {f2bf(a.x), f2bf(a.y), f2bf(a.z), f2bf(a.w),
                           f2bf(b.x), f2bf(b.y), f2bf(b.z), f2bf(b.w)};
    *(uint4*)(xb + (size_t)i * 8) = *(const uint4*)r;
  } else if (bid < 7168) {                     // ---- castT5 ----
    __shared__ float tile[32][33];
    int w = bid - 2048;
    int z = w >> 10, within = w & 1023;
    const float* src = z == 0 ? w0 : z == 1 ? w1 : z == 2 ? w2 : z == 3 ? w3 : w4;
    unsigned short* dst = z == 0 ? t0 : z == 1 ? t1 : z == 2 ? t2 : z == 3 ? t3 : t4;
    int c0 = (within & 31) * 32, r0 = (within >> 5) * 32;
    int tx = threadIdx.x & 31, ty = threadIdx.x >> 5;
    #pragma unroll
    for (int i = 0; i < 4; i++)
      tile[ty + i * 8][tx] = src[(size_t)(r0 + ty + i * 8) * 1024 + c0 + tx];
    __syncthreads();
    #pragma unroll
    for (int i = 0; i < 4; i++)
      dst[(size_t)(c0 + ty + i * 8) * 1024 + r0 + tx] = f2bf(tile[tx][ty + i * 8]);
  } else {                                     // ---- wa_pad ----
    int idx = (bid - 7168) * 256 + threadIdx.x;
    int h = idx >> 10, k2 = idx & 1023;
    wa_pad[idx] = (h < 16) ? f2bf(Wa[k2 * 16 + h]) : (unsigned short)0;
  }
}

// ---------------- la partial GEMM: K-split by 8 ----------------
__global__ __launch_bounds__(256) void k_la_gemm(const unsigned short* __restrict__ xb,
    const unsigned short* __restrict__ wa_pad, float* __restrict__ la8) {
  __shared__ unsigned short As[128 * 32];
  __shared__ unsigned short Bs[128 * 32];
  int tid = threadIdx.x;
  int row0 = blockIdx.y * 128;
  int kbeg = blockIdx.x * 128;
  float* Cp = la8 + (size_t)blockIdx.x * (32 * 2048);
  int w = tid >> 6, l = tid & 63;
  int wr = w >> 1, wc = w & 1;
  int lr = l & 15, lk = l >> 4;
  f32x4 acc[4] = {};
  for (int k0 = kbeg; k0 < kbeg + 128; k0 += 32) {
    __syncthreads();
    #pragma unroll
    for (int i = 0; i < 2; i++) {
      int idx = tid + i * 256;
      int r = idx >> 2, c = idx & 3;
      int cs = c ^ ((r >> 1) & 3);
      const unsigned short* srcA = xb + (size_t)(row0 + r) * NM + k0 + cs * 8;
      const unsigned short* srcB = wa_pad + (size_t)r * NM + k0 + cs * 8;
      __builtin_amdgcn_global_load_lds(
          (const __attribute__((address_space(1))) void*)srcA,
          (__attribute__((address_space(3))) void*)((char*)As + (w * 64 + i * 256) * 16),
          16, 0, 0);
      __builtin_amdgcn_global_load_lds(
          (const __attribute__((address_space(1))) void*)srcB,
          (__attribute__((address_space(3))) void*)((char*)Bs + (w * 64 + i * 256) * 16),
          16, 0, 0);
    }
    __syncthreads();
    if (wc == 0) {
      bf16x8 b = *(const bf16x8*)&Bs[lr * 32 + (lk ^ ((lr >> 1) & 3)) * 8];
      #pragma unroll
      for (int m = 0; m < 4; m++) {
        int ra = wr * 64 + m * 16 + lr;
        bf16x8 a = *(const bf16x8*)&As[ra * 32 + (lk ^ ((ra >> 1) & 3)) * 8];
        acc[m] = __builtin_amdgcn_mfma_f32_16x16x32_bf16(a, b, acc[m], 0, 0, 0);
      }
    }
  }
  if (wc == 0) {
    #pragma unroll
    for (int m = 0; m < 4; m++) {
      #pragma unroll
      for (int j = 0; j < 4; j++) {
        int row = row0 + wr * 64 + m * 16 + lk * 4 + j;
        int bb = row >> 11, s = row & 2047;
        Cp[((size_t)(bb * 16 + lr)) * 2048 + s] = acc[m][j];
      }
    }
  }
}

// ---------------- cumsum: sum 8 K-slices + bias, -softplus, scan; zero psum/psq ----------------
__global__ __launch_bounds__(256) void k_cumsum(const float* __restrict__ la8,
    const float* __restrict__ ba, float* __restrict__ cum,
    float* __restrict__ psum, float* __restrict__ psq) {
  int g = blockIdx.x;
  int h = g & 15;
  if (threadIdx.x == 0) { psum[g] = 0.f; psq[g] = 0.f; }
  float bah = ba[h];
  const float* p0 = la8 + (size_t)g * NS;
  float* out = cum + (size_t)g * NS;
  __shared__ float part[256];
  float v[8]; float sum = 0.f;
  int base = threadIdx.x * 8;
  #pragma unroll
  for (int i = 0; i < 8; i++) {
    int s = base + i;
    float z = bah;
    #pragma unroll
    for (int sl = 0; sl < 8; sl++) z += p0[sl * 65536 + s];
    float sp = fmaxf(z, 0.f) + log1pf(expf(-fabsf(z)));
    v[i] = -sp; sum += v[i];
  }
  part[threadIdx.x] = sum;
  __syncthreads();
  for (int off = 1; off < 256; off <<= 1) {
    float add = (threadIdx.x >= off) ? part[threadIdx.x - off] : 0.f;
    __syncthreads();
    part[threadIdx.x] += add;
    __syncthreads();
  }
  float run = (threadIdx.x > 0) ? part[threadIdx.x - 1] : 0.f;
  #pragma unroll
  for (int i = 0; i < 8; i++) { run += v[i]; out[base + i] = run; }
}

// ======================================================================
// k_proj8 (r4-proven, accepted): fused q|k|v|g, 256x256 tile, BK=64,
// counted-vmcnt double buffer, source-swizzled LDS, setprio.
// ======================================================================
__global__ __launch_bounds__(512, 2) void k_proj8(
    const unsigned short* __restrict__ A,
    const unsigned short* __restrict__ Wcat,
    unsigned short* __restrict__ q, unsigned short* __restrict__ k,
    unsigned short* __restrict__ v, unsigned short* __restrict__ g) {
  __shared__ unsigned short Ab[2][256 * 64];   // 64 KB
  __shared__ unsigned short Bb[2][256 * 64];   // 64 KB
  int tid = threadIdx.x;
  int bid = blockIdx.x;                        // 0..255
  int wg = (bid & 7) * 32 + (bid >> 3);        // XCD-bijective swizzle
  int bx = wg & 15, by = wg >> 4;
  int row0 = by * 256, col0 = bx * 256;
  int wid = tid >> 6, lane = tid & 63;
  int WR = wid >> 2, WC = wid & 3;             // 2M x 4N wave grid
  int lr = lane & 15, lk = lane >> 4;

  auto stage = [&](int kt, int bi) {
    #pragma unroll
    for (int i = 0; i < 4; i++) {
      int idx = tid + i * 512;                 // chunk 0..2047
      int r = idx >> 3, c = idx & 7;
      int cs = c ^ (r & 7);                    // pre-swizzled source (T2, rule 21)
      const unsigned short* srcA = A + (size_t)(row0 + r) * NM + kt * 64 + cs * 8;
      __builtin_amdgcn_global_load_lds(
          (const __attribute__((address_space(1))) void*)srcA,
          (__attribute__((address_space(3))) void*)((char*)&Ab[bi][0] + (wid * 64 + i * 512) * 16),
          16, 0, 0);
      const unsigned short* srcB = Wcat + (size_t)(col0 + r) * NM + kt * 64 + cs * 8;
      __builtin_amdgcn_global_load_lds(
          (const __attribute__((address_space(1))) void*)srcB,
          (__attribute__((address_space(3))) void*)((char*)&Bb[bi][0] + (wid * 64 + i * 512) * 16),
          16, 0, 0);
    }
  };

  stage(0, 0);
  stage(1, 1);

  f32x4 acc[8][4] = {};
  for (int kt = 0; kt < 16; ++kt) {
    int bi = kt & 1;
    if (kt < 15) asm volatile("s_waitcnt vmcnt(8)" ::: "memory");
    else         asm volatile("s_waitcnt vmcnt(0)" ::: "memory");
    __builtin_amdgcn_sched_barrier(0);
    __builtin_amdgcn_s_barrier();              // all waves' stages landed

    const char* Ap = (const char*)&Ab[bi][0];
    const char* Bp = (const char*)&Bb[bi][0];
    bf16x8 a0[8], b0[4], a1[8], b1[4];
    #pragma unroll
    for (int m = 0; m < 8; m++) {
      int r = WR * 128 + m * 16 + lr;
      a0[m] = *(const bf16x8*)(Ap + r * 128 + ((lk ^ (r & 7)) * 16));
    }
    #pragma unroll
    for (int n = 0; n < 4; n++) {
      int r = WC * 64 + n * 16 + lr;
      b0[n] = *(const bf16x8*)(Bp + r * 128 + ((lk ^ (r & 7)) * 16));
    }
    #pragma unroll
    for (int m = 0; m < 8; m++)
      #pragma unroll
      for (int n = 0; n < 4; n++)
        acc[m][n] = __builtin_amdgcn_mfma_f32_16x16x32_bf16(a0[m], b0[n], acc[m][n], 0, 0, 0);
    #pragma unroll
    for (int m = 0; m < 8; m++) {
      int r = WR * 128 + m * 16 + lr;
      a1[m] = *(const bf16x8*)(Ap + r * 128 + (((lk + 4) ^ (r & 7)) * 16));
    }
    #pragma unroll
    for (int n = 0; n < 4; n++) {
      int r = WC * 64 + n * 16 + lr;
      b1[n] = *(const bf16x8*)(Bp + r * 128 + (((lk + 4) ^ (r & 7)) * 16));
    }
    asm volatile("s_waitcnt lgkmcnt(0)" ::: "memory");   // all reads of buf bi done
    __builtin_amdgcn_sched_barrier(0);
    __builtin_amdgcn_s_barrier();              // every wave done reading buf bi
    if (kt + 2 < 16) stage(kt + 2, bi);        // overwrite freed buffer
    __builtin_amdgcn_s_setprio(1);
    #pragma unroll
    for (int m = 0; m < 8; m++)
      #pragma unroll
      for (int n = 0; n < 4; n++)
        acc[m][n] = __builtin_amdgcn_mfma_f32_16x16x32_bf16(a1[m], b1[n], acc[m][n], 0, 0, 0);
    __builtin_amdgcn_s_setprio(0);
  }

  // epilogue: zone uniform per block (col0 is 256-aligned within 1024)
  #pragma unroll
  for (int m = 0; m < 8; m++) {
    #pragma unroll
    for (int n = 0; n < 4; n++) {
      int col = col0 + WC * 64 + n * 16 + lr;
      int zone = col >> 10;
      unsigned short* dst = zone == 0 ? q : zone == 1 ? k : zone == 2 ? v : g;
      int cb = col & 1023;
      #pragma unroll
      for (int j = 0; j < 4; j++) {
        int row = row0 + WR * 128 + m * 16 + lk * 4 + j;
        float val = acc[m][n][j];
        if (zone <= 1) val = val / (1.f + expf(-val));        // silu
        else if (zone == 3) val = 1.f / (1.f + expf(-val));   // sigmoid
        dst[(size_t)row * 1024 + cb] = f2bf(val);
      }
    }
  }
}

// ======================================================================
// k_out2: out = u @ Wo^T. 64x128 tile, BK=64 double-buffer, 2-phase.
// Grid 512 = 2 blocks/CU (inter-block TLP hides the vmcnt(0) drain);
// 48 KB LDS. 2x2 wave grid, each wave 32x64 (2x4 frags).
// ======================================================================
__global__ __launch_bounds__(256) void k_out2(const unsigned short* __restrict__ A,
    const unsigned short* __restrict__ Bt, float* __restrict__ C) {
  __shared__ unsigned short As[2][64 * 64];    // 8 KB x2
  __shared__ unsigned short Bs[2][128 * 64];   // 16 KB x2
  int tid = threadIdx.x;
  int bid = blockIdx.x;                        // 0..511
  int wg = (bid & 7) * 64 + (bid >> 3);        // XCD-bijective (512 % 8 == 0)
  int bx = wg & 7, by = wg >> 3;               // 8 col-tiles(128), 64 row-tiles(64)
  int row0 = by * 64, col0 = bx * 128;
  int w = tid >> 6, l = tid & 63;
  int wr = w >> 1, wc = w & 1;
  int lr = l & 15, lk = l >> 4;

  auto stage = [&](int t, int bi) {
    #pragma unroll
    for (int i = 0; i < 2; i++) {              // A tile 64x64 = 512 chunks
      int idx = tid + i * 256;
      int r = idx >> 3, c = idx & 7;
      int cs = c ^ (r & 7);
      const unsigned short* srcA = A + (size_t)(row0 + r) * NM + t * 64 + cs * 8;
      __builtin_amdgcn_global_load_lds(
          (const __attribute__((address_space(1))) void*)srcA,
          (__attribute__((address_space(3))) void*)((char*)&As[bi][0] + idx * 16),
          16, 0, 0);
    }
    #pragma unroll
    for (int i = 0; i < 4; i++) {              // B tile 128x64 = 1024 chunks
      int idx = tid + i * 256;
      int r = idx >> 3, c = idx & 7;
      int cs = c ^ (r & 7);
      const unsigned short* srcB = Bt + (size_t)(col0 + r) * NM + t * 64 + cs * 8;
      __builtin_amdgcn_global_load_lds(
          (const __attribute__((address_space(1))) void*)srcB,
          (__attribute__((address_space(3))) void*)((char*)&Bs[bi][0] + idx * 16),
          16, 0, 0);
    }
  };

  stage(0, 0);
  asm volatile("s_waitcnt vmcnt(0)" ::: "memory");
  __builtin_amdgcn_s_barrier();

  f32x4 acc[2][4] = {};
  int cur = 0;
  for (int t = 0; t < 16; ++t) {
    if (t < 15) stage(t + 1, cur ^ 1);
    const char* Ap = (const char*)&As[cur][0];
    const char* Bp = (const char*)&Bs[cur][0];
    bf16x8 a[2][2], b[4][2];
    #pragma unroll
    for (int m = 0; m < 2; m++) {
      int ra = wr * 32 + m * 16 + lr;
      #pragma unroll
      for (int kk = 0; kk < 2; kk++)
        a[m][kk] = *(const bf16x8*)(Ap + ra * 128 + (((kk * 4 + lk) ^ (ra & 7)) * 16));
    }
    #pragma unroll
    for (int n = 0; n < 4; n++) {
      int rb = wc * 64 + n * 16 + lr;
      #pragma unroll
      for (int kk = 0; kk < 2; kk++)
        b[n][kk] = *(const bf16x8*)(Bp + rb * 128 + (((kk * 4 + lk) ^ (rb & 7)) * 16));
    }
    __builtin_amdgcn_s_setprio(1);
    #pragma unroll
    for (int kk = 0; kk < 2; kk++)
      #pragma unroll
      for (int m = 0; m < 2; m++)
        #pragma unroll
        for (int n = 0; n < 4; n++)
          acc[m][n] = __builtin_amdgcn_mfma_f32_16x16x32_bf16(a[m][kk], b[n][kk], acc[m][n], 0, 0, 0);
    __builtin_amdgcn_s_setprio(0);
    asm volatile("s_waitcnt vmcnt(0)" ::: "memory");
    __builtin_amdgcn_s_barrier();
    cur ^= 1;
  }
  #pragma unroll
  for (int m = 0; m < 2; m++)
    #pragma unroll
    for (int n = 0; n < 4; n++)
      #pragma unroll
      for (int j = 0; j < 4; j++) {
        int row = row0 + wr * 32 + m * 16 + lk * 4 + j;
        int col = col0 + wc * 64 + n * 16 + lr;
        C[(size_t)row * NM + col] = acc[m][n][j];
      }
}

// ---------------- MFMA attention + fused GroupNorm partial stats (o: bf16) ----------------
// T14 async-split: K/V global loads for tile jt+1 issued before the QKT/PV
// phases of tile jt. 3 barriers per j-tile. Wave-shfl epilogue reduce.
__global__ __launch_bounds__(256) void k_attn(const unsigned short* __restrict__ q,
    const unsigned short* __restrict__ kk, const unsigned short* __restrict__ vv,
    const float* __restrict__ cum, unsigned short* __restrict__ o,
    float* __restrict__ psum, float* __restrict__ psq) {
  int it = blockIdx.x, h = blockIdx.y, b = blockIdx.z;
  int i0 = it * 64;
  __shared__ unsigned short Qs[64 * 64];
  __shared__ unsigned short Ks[64 * 64];
  __shared__ unsigned short Ps[64 * 64];
  __shared__ unsigned short Vt[64 * 66];       // [d][j], stride 66 halfwords
  __shared__ float ci[64], cj[64];
  __shared__ int jlo_s;
  int tid = threadIdx.x;
  int w = tid >> 6, lane = tid & 63;
  int cl = lane & 15, hi = lane >> 4;
  const size_t hb = (size_t)b * NS * NDI + (size_t)h * ND;
  const float* cumh = cum + (size_t)(b * NH + h) * NS;

  #pragma unroll
  for (int lp = 0; lp < 2; lp++) {
    int idx = tid + lp * 256;
    int r = idx >> 3, cb = (idx & 7) * 16;
    uint4 t = *(const uint4*)(q + hb + (size_t)(i0 + r) * NDI + (cb >> 1));
    *(uint4*)((char*)Qs + r * 128 + (cb ^ ((r & 7) << 4))) = t;
  }
  if (tid < 64) ci[tid] = cumh[i0 + tid];
  if (tid < 64) {
    int jt = tid;
    bool ok = (jt <= it) && (cumh[i0] - cumh[jt * 64 + 63] >= -25.f);
    unsigned long long mask = __ballot(ok);
    if (tid == 0) jlo_s = (int)__builtin_ctzll(mask);
  }
  __syncthreads();
  int jlo = jlo_s;

  int arow = w * 16 + cl;
  int xr = (cl & 7) << 4;
  const char* Qb = (const char*)Qs + arow * 128;
  const char* Pb = (const char*)Ps + arow * 128;
  f32x4 acco[4] = {};

  // T14 preload for first live tile
  uint4 tK[2], tV[2];
  auto gload = [&](int j0) {
    #pragma unroll
    for (int lp = 0; lp < 2; lp++) {
      int idx = tid + lp * 256;
      int r = idx >> 3, c8h = (idx & 7) * 8;
      tK[lp] = *(const uint4*)(kk + hb + (size_t)(j0 + r) * NDI + c8h);
      tV[lp] = *(const uint4*)(vv + hb + (size_t)(j0 + r) * NDI + c8h);
    }
  };
  if (jlo <= it) gload(jlo * 64);

  for (int jt = jlo; jt <= it; jt++) {
    int j0 = jt * 64;
    __syncthreads();                           // A: prior iter's LDS reads done
    if (tid < 64) cj[tid] = cumh[j0 + tid];
    #pragma unroll
    for (int lp = 0; lp < 2; lp++) {           // LDS writes from preloaded regs
      int idx = tid + lp * 256;
      int r = idx >> 3, cb = (idx & 7) * 16;
      *(uint4*)((char*)Ks + r * 128 + (cb ^ ((r & 7) << 4))) = tK[lp];
      unsigned short us[8]; *(uint4*)us = tV[lp];
      int c8 = (idx & 7) * 8;
      #pragma unroll
      for (int e = 0; e < 8; e++) Vt[(c8 + e) * 66 + r] = us[e];
    }
    if (jt + 1 <= it) gload(j0 + 64);          // prefetch next tile (in flight over QKT/PV)
    __syncthreads();                           // B: cj + K/V visible
    bf16x8 a0 = *(const bf16x8*)(Qb + ((hi * 16) ^ xr));
    bf16x8 a1 = *(const bf16x8*)(Qb + ((64 + hi * 16) ^ xr));
    f32x4 accs[4] = {};
    #pragma unroll
    for (int jtile = 0; jtile < 4; jtile++) {
      const char* Kb = (const char*)Ks + (jtile * 16 + cl) * 128;
      bf16x8 b0 = *(const bf16x8*)(Kb + ((hi * 16) ^ xr));
      bf16x8 b1 = *(const bf16x8*)(Kb + ((64 + hi * 16) ^ xr));
      accs[jtile] = __builtin_amdgcn_mfma_f32_16x16x32_bf16(a0, b0, accs[jtile], 0, 0, 0);
      accs[jtile] = __builtin_amdgcn_mfma_f32_16x16x32_bf16(a1, b1, accs[jtile], 0, 0, 0);
    }
    #pragma unroll
    for (int jtile = 0; jtile < 4; jtile++) {
      #pragma unroll
      for (int reg = 0; reg < 4; reg++) {
        int irl = w * 16 + hi * 4 + reg;
        int jl = jtile * 16 + cl;
        float dec = ((j0 + jl) <= (i0 + irl)) ? __expf(ci[irl] - cj[jl]) : 0.f;
        float pv = accs[jtile][reg] * dec;
        *(unsigned short*)((char*)Ps + irl * 128 + ((2 * jl) ^ ((irl & 7) << 4))) = f2bf(pv);
      }
    }
    __syncthreads();                           // C: Ps visible
    #pragma unroll
    for (int kk2 = 0; kk2 < 2; kk2++) {
      bf16x8 pa = *(const bf16x8*)(Pb + ((kk2 * 64 + hi * 16) ^ xr));
      #pragma unroll
      for (int dt = 0; dt < 4; dt++) {
        const unsigned int* vp = (const unsigned int*)(Vt + (dt * 16 + cl) * 66 + kk2 * 32 + hi * 8);
        uint4 tmp;
        tmp.x = vp[0]; tmp.y = vp[1]; tmp.z = vp[2]; tmp.w = vp[3];
        bf16x8 vb = *(const bf16x8*)&tmp;
        acco[dt] = __builtin_amdgcn_mfma_f32_16x16x32_bf16(pa, vb, acco[dt], 0, 0, 0);
      }
    }
  }
  #pragma unroll
  for (int dt = 0; dt < 4; dt++) {
    #pragma unroll
    for (int reg = 0; reg < 4; reg++) {
      int row = i0 + w * 16 + hi * 4 + reg;
      o[hb + (size_t)row * NDI + dt * 16 + cl] = f2bf(acco[dt][reg]);
    }
  }
  // fused GroupNorm partial stats: wave shfl reduce + 2 barriers
  float sm = 0.f, sq = 0.f;
  #pragma unroll
  for (int dt = 0; dt < 4; dt++)
    #pragma unroll
    for (int reg = 0; reg < 4; reg++) { float t2 = acco[dt][reg]; sm += t2; sq += t2 * t2; }
  #pragma unroll
  for (int off = 32; off > 0; off >>= 1) {
    sm += __shfl_down(sm, off, 64);
    sq += __shfl_down(sq, off, 64);
  }
  __syncthreads();                             // all PV reads of Ps done (scratch reuse)
  float* ws2 = (float*)Ps;
  if (lane == 0) { ws2[w * 2] = sm; ws2[w * 2 + 1] = sq; }
  __syncthreads();
  if (tid == 0) {
    float S = 0.f, Q2 = 0.f;
    #pragma unroll
    for (int i = 0; i < 4; i++) { S += ws2[i * 2]; Q2 += ws2[i * 2 + 1]; }
    atomicAdd(&psum[b * NH + h], S);
    atomicAdd(&psq[b * NH + h], Q2);
  }
}

// ---------------- u = (groupnorm(o)*w+b)*gate, bf16 out (stats inline) ----------------
__global__ __launch_bounds__(256) void k_gate(const unsigned short* __restrict__ o,
    const unsigned short* __restrict__ gsig, const float* __restrict__ psum,
    const float* __restrict__ psq, const float* __restrict__ gnw,
    const float* __restrict__ gnb, unsigned short* __restrict__ u) {
  int idx4 = blockIdx.x * 256 + threadIdx.x;
  size_t base = (size_t)idx4 * 4;
  int c = (int)(base & (NDI - 1));
  int row = (int)(base >> 10);
  int b = row >> 11;
  int h = c >> 6;
  int g = b * NH + h;
  float n = (float)(NS * ND);
  float mean = psum[g] / n;
  float var = psq[g] / n - mean * mean;
  float rstd = rsqrtf(var + 1e-5f);
  ushort4 ov = *(const ushort4*)(o + base);
  ushort4 gv = *(const ushort4*)(gsig + base);
  float4 w4 = *(const float4*)(gnw + c);
  float4 b4 = *(const float4*)(gnb + c);
  unsigned short r[4];
  r[0] = f2bf(((bf2f(ov.x) - mean) * rstd * w4.x + b4.x) * bf2f(gv.x));
  r[1] = f2bf(((bf2f(ov.y) - mean) * rstd * w4.y + b4.y) * bf2f(gv.y));
  r[2] = f2bf(((bf2f(ov.z) - mean) * rstd * w4.z + b4.z) * bf2f(gv.z));
  r[3] = f2bf(((bf2f(ov.w) - mean) * rstd * w4.w + b4.w) * bf2f(gv.w));
  *(ushort4*)(u + base) = *(const ushort4*)r;
}

extern "C" void kernel_launch(void* const* d_in, const int* in_sizes, int n_in,
                              void* d_out, int out_size, void* d_ws, size_t ws_size,
                              hipStream_t stream) {
  const float* x   = (const float*)d_in[0];
  const float* Wq  = (const float*)d_in[1];
  const float* Wk  = (const float*)d_in[2];
  const float* Wv  = (const float*)d_in[3];
  const float* Wg  = (const float*)d_in[4];
  const float* Wa  = (const float*)d_in[5];
  const float* ba  = (const float*)d_in[6];
  const float* Wo  = (const float*)d_in[7];
  const float* gnw = (const float*)d_in[8];
  const float* gnb = (const float*)d_in[9];
  float* out = (float*)d_out;

  const size_t NTOK = (size_t)NB * NS;        // 4096
  char* p = (char*)d_ws;
  float* la8 = (float*)p;                 p += (size_t)8 * 32 * NS * 4;   // 2 MB
  float* cum = (float*)p;                 p += (size_t)NB * NH * NS * 4;
  float* psum = (float*)p;                p += 32 * 4;
  float* psq  = (float*)p;                p += 32 * 4;
  p = (char*)(((uintptr_t)p + 255) & ~(uintptr_t)255);
  unsigned short* xb   = (unsigned short*)p; p += NTOK * NM * 2;        // 8 MB
  unsigned short* Wcat = (unsigned short*)p; p += (size_t)4 * NM * NDI * 2; // 8 MB
  unsigned short* wto  = (unsigned short*)p; p += (size_t)NDI * NM * 2;
  unsigned short* wa_pad = (unsigned short*)p; p += (size_t)128 * NM * 2;
  unsigned short* q  = (unsigned short*)p;  p += NTOK * NDI * 2;
  unsigned short* k  = (unsigned short*)p;  p += NTOK * NDI * 2;
  unsigned short* v  = (unsigned short*)p;  p += NTOK * NDI * 2;
  unsigned short* g  = (unsigned short*)p;  p += NTOK * NDI * 2;
  unsigned short* u  = (unsigned short*)p;  p += NTOK * NDI * 2;
  unsigned short* o  = (unsigned short*)p;  p += NTOK * NDI * 2;

  unsigned short* wtq = Wcat;
  unsigned short* wtk = Wcat + (size_t)NM * NDI;
  unsigned short* wtv = Wcat + (size_t)2 * NM * NDI;
  unsigned short* wtg = Wcat + (size_t)3 * NM * NDI;

  k_prep    <<<dim3(7680), 256, 0, stream>>>(x, Wq, Wk, Wv, Wg, Wo, Wa,
                                             xb, wtq, wtk, wtv, wtg, wto, wa_pad);
  k_la_gemm <<<dim3(8, 32), 256, 0, stream>>>(xb, wa_pad, la8);
  k_cumsum  <<<dim3(NB * NH), 256, 0, stream>>>(la8, ba, cum, psum, psq);
  k_proj8   <<<dim3(256), 512, 0, stream>>>(xb, Wcat, q, k, v, g);
  k_attn    <<<dim3(32, NH, NB), 256, 0, stream>>>(q, k, v, cum, o, psum, psq);
  k_gate    <<<dim3(4096), 256, 0, stream>>>(o, g, psum, psq, gnw, gnb, u);
  k_out2    <<<dim3(512), 256, 0, stream>>>(u, wto, out);
}